// Round 4
// baseline (2608.952 us; speedup 1.0000x reference)
//
#include <hip/hip_runtime.h>
#include <hip/hip_bf16.h>

// Problem constants
#define BB 64
#define TT 512
#define DD 128
#define HH 256
#define G4 1024   // 4*H
#define CC 50

typedef __bf16 bf16x8 __attribute__((ext_vector_type(8)));
typedef float  f32x4  __attribute__((ext_vector_type(4)));
typedef _Float16 h16x2 __attribute__((ext_vector_type(2)));

#if defined(__has_builtin)
#if __has_builtin(__builtin_amdgcn_fdot2)
#define HAS_FDOT2 1
#endif
#endif

__device__ __forceinline__ float bl16(unsigned u) { return __uint_as_float(u << 16); }
__device__ __forceinline__ float bh16(unsigned u) { return __uint_as_float(u & 0xffff0000u); }

__device__ __forceinline__ float sigf(float x) {
    return 1.f / (1.f + __expf(-x));
}
__device__ __forceinline__ float tanh_s(float x) {
    float ax = fabsf(x);
    float e = __expf(-2.f * ax);
    float r = (1.f - e) / (1.f + e);
    return copysignf(r, x);
}

// 8-element f16 dot product chunk, f32 accumulate
__device__ __forceinline__ float dot8(float acc, uint4 w, uint4 h) {
#ifdef HAS_FDOT2
    acc = __builtin_amdgcn_fdot2(__builtin_bit_cast(h16x2, w.x),
                                 __builtin_bit_cast(h16x2, h.x), acc, false);
    acc = __builtin_amdgcn_fdot2(__builtin_bit_cast(h16x2, w.y),
                                 __builtin_bit_cast(h16x2, h.y), acc, false);
    acc = __builtin_amdgcn_fdot2(__builtin_bit_cast(h16x2, w.z),
                                 __builtin_bit_cast(h16x2, h.z), acc, false);
    acc = __builtin_amdgcn_fdot2(__builtin_bit_cast(h16x2, w.w),
                                 __builtin_bit_cast(h16x2, h.w), acc, false);
#else
    {
        h16x2 a = __builtin_bit_cast(h16x2, w.x), b = __builtin_bit_cast(h16x2, h.x);
        acc = fmaf((float)a.x, (float)b.x, acc); acc = fmaf((float)a.y, (float)b.y, acc);
        a = __builtin_bit_cast(h16x2, w.y); b = __builtin_bit_cast(h16x2, h.y);
        acc = fmaf((float)a.x, (float)b.x, acc); acc = fmaf((float)a.y, (float)b.y, acc);
        a = __builtin_bit_cast(h16x2, w.z); b = __builtin_bit_cast(h16x2, h.z);
        acc = fmaf((float)a.x, (float)b.x, acc); acc = fmaf((float)a.y, (float)b.y, acc);
        a = __builtin_bit_cast(h16x2, w.w); b = __builtin_bit_cast(h16x2, h.w);
        acc = fmaf((float)a.x, (float)b.x, acc); acc = fmaf((float)a.y, (float)b.y, acc);
    }
#endif
    return acc;
}

// ---------------------------------------------------------------------------
// Kernel 0: f32 -> bf16 conversion (8 elements/thread)
// ---------------------------------------------------------------------------
__global__ __launch_bounds__(256) void k_cvt(
    const float* __restrict__ src, __hip_bfloat16* __restrict__ dst, int n)
{
    int i = (blockIdx.x * 256 + threadIdx.x) * 8;
    if (i + 8 <= n) {
        float4 a = *(const float4*)(src + i);
        float4 b = *(const float4*)(src + i + 4);
        __hip_bfloat16 o[8];
        o[0] = __float2bfloat16(a.x); o[1] = __float2bfloat16(a.y);
        o[2] = __float2bfloat16(a.z); o[3] = __float2bfloat16(a.w);
        o[4] = __float2bfloat16(b.x); o[5] = __float2bfloat16(b.y);
        o[6] = __float2bfloat16(b.z); o[7] = __float2bfloat16(b.w);
        *(uint4*)(dst + i) = *(const uint4*)o;
    }
}

// ---------------------------------------------------------------------------
// Kernel 0b: pack W_hh (f32 [1024][256]) -> f16.
// Wp[((dir*32 + kc)*4 + g)*256 + j] = 8 f16 of row (g*256 + j), k in
// [8kc, 8kc+8).  k_lstm thread tid = half*256+j consumes kc = kcl + 16*half.
// ---------------------------------------------------------------------------
__global__ __launch_bounds__(256) void k_pack(
    const float* __restrict__ Wf, const float* __restrict__ Wb,
    uint4* __restrict__ Wp)
{
    int blk = blockIdx.x;            // 256 blocks = dir*128 + kc*4 + g
    int g   = blk & 3;
    int kc  = (blk >> 2) & 31;
    int dir = blk >> 7;
    int j = threadIdx.x;
    int row = g * 256 + j;
    const float* src = (dir ? Wb : Wf) + (size_t)row * 256 + kc * 8;
    float4 a = *(const float4*)src;
    float4 b = *(const float4*)(src + 4);
    _Float16 o[8];
    o[0] = (_Float16)a.x; o[1] = (_Float16)a.y;
    o[2] = (_Float16)a.z; o[3] = (_Float16)a.w;
    o[4] = (_Float16)b.x; o[5] = (_Float16)b.y;
    o[6] = (_Float16)b.z; o[7] = (_Float16)b.w;
    Wp[((size_t)(dir * 32 + kc) * 4 + g) * 256 + j] = *(const uint4*)o;
}

// ---------------------------------------------------------------------------
// Kernel 1: xg = emb[words] @ W_ih^T + b, LDS-staged MFMA GEMM (unchanged).
// ---------------------------------------------------------------------------
__global__ __launch_bounds__(256, 2) void k_xg(
    const int* __restrict__ words,
    const float* __restrict__ embf,           // f32 [50000][128]
    const __hip_bfloat16* __restrict__ Wih,   // bf16 [2048][128] (fwd|bwd)
    const float* __restrict__ bfv, const float* __restrict__ bbv,
    __hip_bfloat16* __restrict__ xg)
{
    __shared__ __align__(16) __hip_bfloat16 A[64][136];
    int tid = threadIdx.x;
    int bt0 = blockIdx.x * 64;

    {
        int r = tid >> 2;
        int c0 = (tid & 3) * 32;
        int word = words[bt0 + r];
        const float* src = embf + (size_t)word * DD + c0;
#pragma unroll
        for (int i = 0; i < 8; ++i) {
            float4 v = *(const float4*)(src + i * 4);
            __hip_bfloat16 o[4] = {__float2bfloat16(v.x), __float2bfloat16(v.y),
                                   __float2bfloat16(v.z), __float2bfloat16(v.w)};
            *(uint2*)&A[r][c0 + i * 4] = *(const uint2*)o;
        }
    }
    __syncthreads();

    int wave = tid >> 6, lane = tid & 63;
    int m = lane & 15, quad = lane >> 4;

    bf16x8 afr[4][4];
#pragma unroll
    for (int ms = 0; ms < 4; ++ms)
#pragma unroll
        for (int kf = 0; kf < 4; ++kf)
            afr[ms][kf] = *(const bf16x8*)&A[ms * 16 + m][quad * 8 + kf * 32];

#pragma unroll 1
    for (int i = 0; i < 32; ++i) {
        int nt = wave * 32 + i;
        int gate_g = nt * 16 + m;            // 0..2047
        int dir = gate_g >> 10;
        int gate = gate_g & 1023;
        const __hip_bfloat16* brow = Wih + (size_t)gate_g * DD + quad * 8;
        bf16x8 bfr[4];
#pragma unroll
        for (int kf = 0; kf < 4; ++kf) bfr[kf] = *(const bf16x8*)(brow + kf * 32);
        float bv = dir ? bbv[gate] : bfv[gate];
        size_t dbase = (size_t)dir * (size_t)(BB * TT * G4);

#pragma unroll
        for (int ms = 0; ms < 4; ++ms) {
            f32x4 acc = {0.f, 0.f, 0.f, 0.f};
#pragma unroll
            for (int kf = 0; kf < 4; ++kf)
                acc = __builtin_amdgcn_mfma_f32_16x16x32_bf16(afr[ms][kf], bfr[kf], acc, 0, 0, 0);
#pragma unroll
            for (int r = 0; r < 4; ++r) {
                int btrow = bt0 + ms * 16 + quad * 4 + r;
                xg[dbase + (size_t)btrow * G4 + gate] = __float2bfloat16(acc[r] + bv);
            }
        }
    }
}

// ---------------------------------------------------------------------------
// Kernel 2: LSTM recurrence v8 — designed UNDER the allocator's 128-VGPR
// target instead of against it (rounds 0-3: any weight array pushing
// pressure past ~128 gets sunk/streamed regardless of pins).
// 128 blocks x 512 threads (8 waves). Thread tid=half*256+j: all 4 gates of
// hidden j over K-half. Per thread 64 weight chunks (uint4):
//   - kcl 0..1   (8 chunks, 32 VGPR) reg-held, per-iter pinned. Fits budget.
//   - kcl 2..11  (40 chunks) STREAMED from L2 via software-pipelined
//     register double-buffer; rolling pointers (net advance 0/iter) are
//     laundered each iter so LICM can't hoist the periodic loads.
//   - kcl 12..15 (16 chunks, 128 KB) LDS-resident.
// Stream = 320 KB/block/step (vs 512 full): 16 blk/XCD * 320KB / 1800 B/cy
// ≈ 2850 cy/step vs measured 4330 all-stream.
// ---------------------------------------------------------------------------
#define GLOAD(BUF, P) {                                   \
    BUF[0] = *(const uint4*)((P));                        \
    BUF[1] = *(const uint4*)((P) + 4096);                 \
    BUF[2] = *(const uint4*)((P) + 8192);                 \
    BUF[3] = *(const uint4*)((P) + 12288); }

#define CONSUME(K, W0, W1, W2, W3) {                      \
    uint4 hv = *(const uint4*)(hrow + (K) * 8);           \
    a0 = dot8(a0, W0, hv); a1 = dot8(a1, W1, hv);         \
    a2 = dot8(a2, W2, hv); a3 = dot8(a3, W3, hv); }

__global__ __launch_bounds__(512, 2)
void k_lstm(
    const __hip_bfloat16* __restrict__ xg,     // [2][B*T][1024] bf16
    const uint4* __restrict__ Wp,              // f16 packed [2][32][4][256]
    const int* __restrict__ seq_len,
    __hip_bfloat16* __restrict__ hcat)         // [B*T][512]
{
    int b = blockIdx.x & 63;
    int dir = blockIdx.x >> 6;
    int tid = threadIdx.x;      // 0..511
    int j   = tid & 255;
    int half = tid >> 8;        // K-half this thread reduces

    __shared__ __align__(16) uint4 wlds[16 * 512];        // 131072 B
    __shared__ __align__(16) _Float16 hbf[2][HH];         //   1024 B
    __shared__ float pbuf[4][HH];                         //   4096 B

    const uint4* Wd = Wp + (size_t)dir * (32 * 4 * 256);

    // reg-held weights: kcl 0..1 (8 chunks = 32 VGPRs)
    uint4 wh[2][4];
#pragma unroll
    for (int kcl = 0; kcl < 2; ++kcl)
#pragma unroll
        for (int g = 0; g < 4; ++g)
            wh[kcl][g] = Wd[(((kcl + 16 * half) * 4 + g) * 256) + j];

    // LDS-resident weights: kcl 12..15 (16 chunks = 128 KB)
#pragma unroll
    for (int kcl = 12; kcl < 16; ++kcl)
#pragma unroll
        for (int g = 0; g < 4; ++g)
            wlds[((kcl - 12) * 4 + g) * 512 + tid] =
                Wd[(((kcl + 16 * half) * 4 + g) * 256) + j];

    // stream base: chunk (q,g) lives at Wbase + (q*4+g)*4096
    const char* Wbase = (const char*)Wd
                      + ((size_t)(16 * half) * 4) * 4096 + (size_t)j * 16;
    const char* pA = Wbase + 2 * 16384;   // even kcl cycle: 2,4,6,8,10
    const char* pB = Wbase + 3 * 16384;   // odd  kcl cycle: 3,5,7,9,11
    uint4 sA[4], sB[4];
    GLOAD(sA, pA); pA += 32768;           // sA=kcl2, pA->kcl4
    GLOAD(sB, pB); pB += 32768;           // sB=kcl3, pB->kcl5

    if (half == 0) hbf[0][j] = (_Float16)0.f;
    float c = 0.f;
    int L = seq_len[b];
    const __hip_bfloat16* xgb = xg + (size_t)dir * (size_t)(BB * TT * G4)
                                   + (size_t)b * TT * G4;

    int tc = dir ? (L - 1) : 0;
    float xv0 = 0.f, xv1 = 0.f, xv2 = 0.f, xv3 = 0.f;
    if (half == 0) {
        const __hip_bfloat16* xr = xgb + (size_t)tc * G4 + j;
        xv0 = __bfloat162float(xr[0]);   xv1 = __bfloat162float(xr[256]);
        xv2 = __bfloat162float(xr[512]); xv3 = __bfloat162float(xr[768]);
    }
    __syncthreads();

#pragma unroll 1
    for (int t = 0; t < TT; ++t) {
        // pin reg-held weights (loop-carried -> remat illegal); launder the
        // rolling stream pointers (net advance 0/iter -> LICM would hoist)
#pragma unroll
        for (int kcl = 0; kcl < 2; ++kcl)
#pragma unroll
            for (int g = 0; g < 4; ++g)
                asm volatile("" : "+v"(wh[kcl][g].x), "+v"(wh[kcl][g].y),
                                  "+v"(wh[kcl][g].z), "+v"(wh[kcl][g].w));
        {
            unsigned long long uA = (unsigned long long)pA;
            unsigned long long uB = (unsigned long long)pB;
            asm volatile("" : "+v"(uA), "+v"(uB));
            pA = (const char*)uA; pB = (const char*)uB;
        }

        int cur = t & 1, nxt = cur ^ 1;
        int tn = t + 1;
        int tcn = dir ? ((tn < L) ? (L - 1 - tn) : tn) : tn;
        bool pf = (tn < TT);
        __hip_bfloat16 p0, p1, p2, p3;
        if (half == 0 && pf) {
            const __hip_bfloat16* xr = xgb + (size_t)tcn * G4 + j;
            p0 = xr[0]; p1 = xr[256]; p2 = xr[512]; p3 = xr[768];
        }

        const _Float16* hrow = &hbf[cur][half * 128];
        float a0 = 0.f, a1 = 0.f, a2 = 0.f, a3 = 0.f;

        // held
        CONSUME(0, wh[0][0], wh[0][1], wh[0][2], wh[0][3]);
        CONSUME(1, wh[1][0], wh[1][1], wh[1][2], wh[1][3]);

        // streamed, double-buffered (consume q, reissue q+2 in same buffer)
        CONSUME(2, sA[0], sA[1], sA[2], sA[3]); GLOAD(sA, pA); pA += 32768;            // ld 4
        CONSUME(3, sB[0], sB[1], sB[2], sB[3]); GLOAD(sB, pB); pB += 32768;            // ld 5
        CONSUME(4, sA[0], sA[1], sA[2], sA[3]); GLOAD(sA, pA); pA += 32768;            // ld 6
        CONSUME(5, sB[0], sB[1], sB[2], sB[3]); GLOAD(sB, pB); pB += 32768;            // ld 7
        CONSUME(6, sA[0], sA[1], sA[2], sA[3]); GLOAD(sA, pA); pA += 32768;            // ld 8
        CONSUME(7, sB[0], sB[1], sB[2], sB[3]); GLOAD(sB, pB); pB += 32768;            // ld 9
        CONSUME(8, sA[0], sA[1], sA[2], sA[3]); GLOAD(sA, pA); pA += 32768 - 163840;   // ld 10, wrap->2
        CONSUME(9, sB[0], sB[1], sB[2], sB[3]); GLOAD(sB, pB); pB += 32768 - 163840;   // ld 11, wrap->3
        CONSUME(10, sA[0], sA[1], sA[2], sA[3]); GLOAD(sA, pA); pA += 32768;           // ld 2 (next t)
        CONSUME(11, sB[0], sB[1], sB[2], sB[3]); GLOAD(sB, pB); pB += 32768;           // ld 3 (next t)

        // LDS-resident
#pragma unroll
        for (int kcl = 12; kcl < 16; ++kcl) {
            uint4 hv = *(const uint4*)(hrow + kcl * 8);
            int m0 = (kcl - 12) * 4;
            uint4 w0 = wlds[(m0 + 0) * 512 + tid];
            uint4 w1 = wlds[(m0 + 1) * 512 + tid];
            uint4 w2 = wlds[(m0 + 2) * 512 + tid];
            uint4 w3 = wlds[(m0 + 3) * 512 + tid];
            a0 = dot8(a0, w0, hv);
            a1 = dot8(a1, w1, hv);
            a2 = dot8(a2, w2, hv);
            a3 = dot8(a3, w3, hv);
        }

        if (half) {
            pbuf[0][j] = a0; pbuf[1][j] = a1;
            pbuf[2][j] = a2; pbuf[3][j] = a3;
        }
        __syncthreads();

        if (half == 0) {
            float gi = a0 + pbuf[0][j] + xv0;
            float gf = a1 + pbuf[1][j] + xv1;
            float gg = a2 + pbuf[2][j] + xv2;
            float go = a3 + pbuf[3][j] + xv3;
            float i_ = sigf(gi), f_ = sigf(gf), G = tanh_s(gg), o_ = sigf(go);
            c = f_ * c + i_ * G;
            float h = o_ * tanh_s(c);
            hbf[nxt][j] = (_Float16)h;
            hcat[((size_t)(b * TT + tc)) * (2 * HH) + dir * HH + j] = __float2bfloat16(h);
            if (pf) {
                xv0 = __bfloat162float(p0); xv1 = __bfloat162float(p1);
                xv2 = __bfloat162float(p2); xv3 = __bfloat162float(p3);
            }
        }
        tc = tcn;
        __syncthreads();
    }
}

// ---------------------------------------------------------------------------
// Kernel 3: feats = hcat @ fc_W^T + fc_b ; logits = log_softmax(feats)
// v2: 4 rows per 256-thread block (one 64-lane wave-team per row) to cut
// the 32768-tiny-block launch overhead. Barriers are team-uniform.
// ---------------------------------------------------------------------------
__global__ __launch_bounds__(256) void k_fc(
    const __hip_bfloat16* __restrict__ hcat,
    const __hip_bfloat16* __restrict__ fcW,
    const float* __restrict__ fcb,
    float* __restrict__ logits)
{
    int team = threadIdx.x >> 6;   // 0..3
    int tid  = threadIdx.x & 63;
    int row  = blockIdx.x * 4 + team;
    __shared__ __align__(16) float hrow[4][2 * HH];
    __shared__ float fbuf[4][CC + 2];

    {
        uint4 v = *(const uint4*)(hcat + (size_t)row * (2 * HH) + tid * 8);
        float* d = &hrow[team][tid * 8];
        d[0] = bl16(v.x); d[1] = bh16(v.x);
        d[2] = bl16(v.y); d[3] = bh16(v.y);
        d[4] = bl16(v.z); d[5] = bh16(v.z);
        d[6] = bl16(v.w); d[7] = bh16(v.w);
    }
    __syncthreads();

    if (tid < CC) {
        float acc = fcb[tid];
        const uint4* wr = (const uint4*)(fcW + (size_t)tid * (2 * HH));
#pragma unroll 8
        for (int kc = 0; kc < 64; ++kc) {
            uint4 wv = wr[kc];
            float4 h0 = *(const float4*)&hrow[team][kc * 8];
            float4 h1 = *(const float4*)&hrow[team][kc * 8 + 4];
            acc = fmaf(bl16(wv.x), h0.x, acc); acc = fmaf(bh16(wv.x), h0.y, acc);
            acc = fmaf(bl16(wv.y), h0.z, acc); acc = fmaf(bh16(wv.y), h0.w, acc);
            acc = fmaf(bl16(wv.z), h1.x, acc); acc = fmaf(bh16(wv.z), h1.y, acc);
            acc = fmaf(bl16(wv.w), h1.z, acc); acc = fmaf(bh16(wv.w), h1.w, acc);
        }
        fbuf[team][tid] = acc;
    }
    __syncthreads();

    float m = -1e30f;
    for (int i = 0; i < CC; ++i) m = fmaxf(m, fbuf[team][i]);
    float s = 0.f;
    for (int i = 0; i < CC; ++i) s += __expf(fbuf[team][i] - m);
    float lns = __logf(s);
    if (tid < CC) logits[(size_t)row * CC + tid] = fbuf[team][tid] - m - lns;
}

// ---------------------------------------------------------------------------
// Kernel 4: CRF forward scan + gold score; per-batch loss -> loss_b[b]
// ---------------------------------------------------------------------------
__global__ __launch_bounds__(256) void k_crf(
    const float* __restrict__ logits,
    const int* __restrict__ target,
    const int* __restrict__ seq_len,
    const float* __restrict__ trans,
    const float* __restrict__ start_s,
    const float* __restrict__ end_s,
    float* __restrict__ loss_b)
{
    const float L2E = 1.4426950408889634f;
    const float LN2 = 0.6931471805599453f;
    int b = blockIdx.x;
    int tid = threadIdx.x;
    int q = tid >> 6;
    int j = tid & 63;
    bool act = (j < CC);
    int L = seq_len[b];
    const float* lg = logits + (size_t)b * TT * CC;

    __shared__ float alpha2[64];
    __shared__ float mpart[4][64];
    __shared__ float spart[4][64];
    __shared__ float red[256];
    __shared__ float nbuf[CC + 2];

    int i0 = q * 13;
    int icnt = min(13, CC - i0);
    float treg[13];
    if (act) {
#pragma unroll
        for (int s = 0; s < 13; ++s)
            if (s < icnt) treg[s] = L2E * trans[(i0 + s) * CC + j];
    }
    if (q == 0 && act) alpha2[j] = L2E * (lg[j] + start_s[j]);
    __syncthreads();

    float v[13];
    for (int t = 1; t < L; ++t) {
        float mq = -1e30f;
        if (act) {
#pragma unroll
            for (int s = 0; s < 13; ++s)
                if (s < icnt) { v[s] = alpha2[i0 + s] + treg[s]; mq = fmaxf(mq, v[s]); }
        }
        mpart[q][j] = mq;
        __syncthreads();
        float M = fmaxf(fmaxf(mpart[0][j], mpart[1][j]), fmaxf(mpart[2][j], mpart[3][j]));
        float sq = 0.f;
        if (act) {
#pragma unroll
            for (int s = 0; s < 13; ++s)
                if (s < icnt) sq += exp2f(v[s] - M);
        }
        spart[q][j] = sq;
        __syncthreads();
        if (q == 0 && act) {
            float S = spart[0][j] + spart[1][j] + spart[2][j] + spart[3][j];
            alpha2[j] = M + log2f(S) + L2E * lg[(size_t)t * CC + j];
        }
        __syncthreads();
    }

    if (q == 0 && act) nbuf[j] = alpha2[j] + L2E * end_s[j];

    float gp = 0.f;
    const int* tg = target + b * TT;
    for (int t = tid; t < TT; t += 256) {
        if (t < L) {
            int c = tg[t];
            gp += lg[(size_t)t * CC + c];
            if (t >= 1) gp += trans[tg[t - 1] * CC + c];
        }
    }
    red[tid] = gp;
    __syncthreads();

    if (tid == 0) {
        float m2 = -1e30f;
        for (int i = 0; i < CC; ++i) m2 = fmaxf(m2, nbuf[i]);
        float s2 = 0.f;
        for (int i = 0; i < CC; ++i) s2 += exp2f(nbuf[i] - m2);
        float norm_nat = (m2 + log2f(s2)) * LN2;
        float g = 0.f;
        for (int i = 0; i < 256; ++i) g += red[i];
        g += start_s[tg[0]] + end_s[tg[L - 1]];
        loss_b[b] = norm_nat - g;
    }
}

// Parallel final reduction (one wave)
__global__ void k_fin(const float* __restrict__ loss_b, float* __restrict__ out)
{
    int t = threadIdx.x;
    float v = loss_b[t];
#pragma unroll
    for (int o = 32; o > 0; o >>= 1) v += __shfl_down(v, o);
    if (t == 0) out[0] = v * (1.f / BB);
}

// ---------------------------------------------------------------------------
extern "C" void kernel_launch(void* const* d_in, const int* in_sizes, int n_in,
                              void* d_out, int out_size, void* d_ws, size_t ws_size,
                              hipStream_t stream)
{
    const int* words   = (const int*)d_in[0];
    const int* target  = (const int*)d_in[1];
    const int* seq_len = (const int*)d_in[2];
    const float* emb    = (const float*)d_in[3];
    const float* W_ih_f = (const float*)d_in[4];
    const float* W_hh_f = (const float*)d_in[5];
    const float* b_f    = (const float*)d_in[6];
    const float* W_ih_b = (const float*)d_in[7];
    const float* W_hh_b = (const float*)d_in[8];
    const float* b_b    = (const float*)d_in[9];
    const float* fc_W   = (const float*)d_in[10];
    const float* fc_b   = (const float*)d_in[11];
    const float* trans  = (const float*)d_in[12];
    const float* start_s= (const float*)d_in[13];
    const float* end_s  = (const float*)d_in[14];

    char* ws = (char*)d_ws;
    // workspace layout (bytes):
    //   xg     : 134217728                         @ 0
    //   hcat   :  33554432                         @ 134217728
    //   logits :   6553600                         @ 167772160
    //     (Wp f16 lstm pack, 1 MB, overlaps logits: consumed by k_lstm
    //      BEFORE k_fc writes logits)
    //   loss_b :       256                         @ 174325760
    //   wihall :    524288  (bf16 [2048][128])     @ 174326016
    //   fcw_bf :     51200                         @ 174850304
    __hip_bfloat16* xg     = (__hip_bfloat16*)ws;
    __hip_bfloat16* hcat   = (__hip_bfloat16*)(ws + 134217728);
    float*          logits = (float*)(ws + 167772160);
    uint4*          Wp     = (uint4*)(ws + 167772160);
    float*          loss_b = (float*)(ws + 174325760);
    __hip_bfloat16* wihall = (__hip_bfloat16*)(ws + 174326016);
    __hip_bfloat16* fcw_bf = (__hip_bfloat16*)(ws + 174850304);

    k_cvt<<<64,  256, 0, stream>>>(W_ih_f, wihall,          131072);
    k_cvt<<<64,  256, 0, stream>>>(W_ih_b, wihall + 131072, 131072);
    k_cvt<<<13,  256, 0, stream>>>(fc_W,   fcw_bf,          25600);
    k_pack<<<256, 256, 0, stream>>>(W_hh_f, W_hh_b, Wp);

    k_xg  <<<512, 256, 0, stream>>>(words, emb, wihall, b_f, b_b, xg);
    k_lstm<<<128, 512, 0, stream>>>(xg, Wp, seq_len, hcat);
    k_fc  <<<8192, 256, 0, stream>>>(hcat, fcw_bf, fc_b, logits);
    k_crf <<<64, 256, 0, stream>>>(logits, target, seq_len, trans, start_s, end_s, loss_b);
    k_fin <<<1, 64, 0, stream>>>(loss_b, (float*)d_out);
}

// Round 5
// 2396.194 us; speedup vs baseline: 1.0888x; 1.0888x over previous
//
#include <hip/hip_runtime.h>
#include <hip/hip_bf16.h>

// Problem constants
#define BB 64
#define TT 512
#define DD 128
#define HH 256
#define G4 1024   // 4*H
#define CC 50

typedef __bf16 bf16x8 __attribute__((ext_vector_type(8)));
typedef float  f32x4  __attribute__((ext_vector_type(4)));
typedef _Float16 h16x2 __attribute__((ext_vector_type(2)));

#if defined(__has_builtin)
#if __has_builtin(__builtin_amdgcn_fdot2)
#define HAS_FDOT2 1
#endif
#endif

__device__ __forceinline__ float bl16(unsigned u) { return __uint_as_float(u << 16); }
__device__ __forceinline__ float bh16(unsigned u) { return __uint_as_float(u & 0xffff0000u); }

__device__ __forceinline__ float sigf(float x) {
    return 1.f / (1.f + __expf(-x));
}
__device__ __forceinline__ float tanh_s(float x) {
    float ax = fabsf(x);
    float e = __expf(-2.f * ax);
    float r = (1.f - e) / (1.f + e);
    return copysignf(r, x);
}

// 8-element f16 dot product chunk, f32 accumulate
__device__ __forceinline__ float dot8(float acc, uint4 w, uint4 h) {
#ifdef HAS_FDOT2
    acc = __builtin_amdgcn_fdot2(__builtin_bit_cast(h16x2, w.x),
                                 __builtin_bit_cast(h16x2, h.x), acc, false);
    acc = __builtin_amdgcn_fdot2(__builtin_bit_cast(h16x2, w.y),
                                 __builtin_bit_cast(h16x2, h.y), acc, false);
    acc = __builtin_amdgcn_fdot2(__builtin_bit_cast(h16x2, w.z),
                                 __builtin_bit_cast(h16x2, h.z), acc, false);
    acc = __builtin_amdgcn_fdot2(__builtin_bit_cast(h16x2, w.w),
                                 __builtin_bit_cast(h16x2, h.w), acc, false);
#else
    {
        h16x2 a = __builtin_bit_cast(h16x2, w.x), b = __builtin_bit_cast(h16x2, h.x);
        acc = fmaf((float)a.x, (float)b.x, acc); acc = fmaf((float)a.y, (float)b.y, acc);
        a = __builtin_bit_cast(h16x2, w.y); b = __builtin_bit_cast(h16x2, h.y);
        acc = fmaf((float)a.x, (float)b.x, acc); acc = fmaf((float)a.y, (float)b.y, acc);
        a = __builtin_bit_cast(h16x2, w.z); b = __builtin_bit_cast(h16x2, h.z);
        acc = fmaf((float)a.x, (float)b.x, acc); acc = fmaf((float)a.y, (float)b.y, acc);
        a = __builtin_bit_cast(h16x2, w.w); b = __builtin_bit_cast(h16x2, h.w);
        acc = fmaf((float)a.x, (float)b.x, acc); acc = fmaf((float)a.y, (float)b.y, acc);
    }
#endif
    return acc;
}

// ---------------------------------------------------------------------------
// Kernel 0: f32 -> bf16 conversion (8 elements/thread)
// ---------------------------------------------------------------------------
__global__ __launch_bounds__(256) void k_cvt(
    const float* __restrict__ src, __hip_bfloat16* __restrict__ dst, int n)
{
    int i = (blockIdx.x * 256 + threadIdx.x) * 8;
    if (i + 8 <= n) {
        float4 a = *(const float4*)(src + i);
        float4 b = *(const float4*)(src + i + 4);
        __hip_bfloat16 o[8];
        o[0] = __float2bfloat16(a.x); o[1] = __float2bfloat16(a.y);
        o[2] = __float2bfloat16(a.z); o[3] = __float2bfloat16(a.w);
        o[4] = __float2bfloat16(b.x); o[5] = __float2bfloat16(b.y);
        o[6] = __float2bfloat16(b.z); o[7] = __float2bfloat16(b.w);
        *(uint4*)(dst + i) = *(const uint4*)o;
    }
}

// ---------------------------------------------------------------------------
// Kernel 0b: pack W_hh (f32 [1024][256]) -> f16.
// Wp[((dir*32 + kc)*4 + g)*256 + j] = 8 f16 of row (g*256 + j), k in
// [8kc, 8kc+8).  k_lstm thread tid = half*256+j consumes kc = kcl + 16*half.
// ---------------------------------------------------------------------------
__global__ __launch_bounds__(256) void k_pack(
    const float* __restrict__ Wf, const float* __restrict__ Wb,
    uint4* __restrict__ Wp)
{
    int blk = blockIdx.x;            // 256 blocks = dir*128 + kc*4 + g
    int g   = blk & 3;
    int kc  = (blk >> 2) & 31;
    int dir = blk >> 7;
    int j = threadIdx.x;
    int row = g * 256 + j;
    const float* src = (dir ? Wb : Wf) + (size_t)row * 256 + kc * 8;
    float4 a = *(const float4*)src;
    float4 b = *(const float4*)(src + 4);
    _Float16 o[8];
    o[0] = (_Float16)a.x; o[1] = (_Float16)a.y;
    o[2] = (_Float16)a.z; o[3] = (_Float16)a.w;
    o[4] = (_Float16)b.x; o[5] = (_Float16)b.y;
    o[6] = (_Float16)b.z; o[7] = (_Float16)b.w;
    Wp[((size_t)(dir * 32 + kc) * 4 + g) * 256 + j] = *(const uint4*)o;
}

// ---------------------------------------------------------------------------
// Kernel 1: xg = emb[words] @ W_ih^T + b, LDS-staged MFMA GEMM (unchanged).
// ---------------------------------------------------------------------------
__global__ __launch_bounds__(256, 2) void k_xg(
    const int* __restrict__ words,
    const float* __restrict__ embf,           // f32 [50000][128]
    const __hip_bfloat16* __restrict__ Wih,   // bf16 [2048][128] (fwd|bwd)
    const float* __restrict__ bfv, const float* __restrict__ bbv,
    __hip_bfloat16* __restrict__ xg)
{
    __shared__ __align__(16) __hip_bfloat16 A[64][136];
    int tid = threadIdx.x;
    int bt0 = blockIdx.x * 64;

    {
        int r = tid >> 2;
        int c0 = (tid & 3) * 32;
        int word = words[bt0 + r];
        const float* src = embf + (size_t)word * DD + c0;
#pragma unroll
        for (int i = 0; i < 8; ++i) {
            float4 v = *(const float4*)(src + i * 4);
            __hip_bfloat16 o[4] = {__float2bfloat16(v.x), __float2bfloat16(v.y),
                                   __float2bfloat16(v.z), __float2bfloat16(v.w)};
            *(uint2*)&A[r][c0 + i * 4] = *(const uint2*)o;
        }
    }
    __syncthreads();

    int wave = tid >> 6, lane = tid & 63;
    int m = lane & 15, quad = lane >> 4;

    bf16x8 afr[4][4];
#pragma unroll
    for (int ms = 0; ms < 4; ++ms)
#pragma unroll
        for (int kf = 0; kf < 4; ++kf)
            afr[ms][kf] = *(const bf16x8*)&A[ms * 16 + m][quad * 8 + kf * 32];

#pragma unroll 1
    for (int i = 0; i < 32; ++i) {
        int nt = wave * 32 + i;
        int gate_g = nt * 16 + m;            // 0..2047
        int dir = gate_g >> 10;
        int gate = gate_g & 1023;
        const __hip_bfloat16* brow = Wih + (size_t)gate_g * DD + quad * 8;
        bf16x8 bfr[4];
#pragma unroll
        for (int kf = 0; kf < 4; ++kf) bfr[kf] = *(const bf16x8*)(brow + kf * 32);
        float bv = dir ? bbv[gate] : bfv[gate];
        size_t dbase = (size_t)dir * (size_t)(BB * TT * G4);

#pragma unroll
        for (int ms = 0; ms < 4; ++ms) {
            f32x4 acc = {0.f, 0.f, 0.f, 0.f};
#pragma unroll
            for (int kf = 0; kf < 4; ++kf)
                acc = __builtin_amdgcn_mfma_f32_16x16x32_bf16(afr[ms][kf], bfr[kf], acc, 0, 0, 0);
#pragma unroll
            for (int r = 0; r < 4; ++r) {
                int btrow = bt0 + ms * 16 + quad * 4 + r;
                xg[dbase + (size_t)btrow * G4 + gate] = __float2bfloat16(acc[r] + bv);
            }
        }
    }
}

// ---------------------------------------------------------------------------
// Kernel 2: LSTM recurrence v9 — batch-paired weight streaming.
// The k_lstm stage is L2-BW-bound on re-streaming W_hh (v7: 16 blk/XCD *
// 512 KB = 8 MB/step/XCD = 4330 cy/step measured = stream roofline).
// Fix: 64 blocks, each handles TWO batches of one dir -> each streamed
// weight chunk is used twice. Stream/XCD: 8 blk * 384 KB = 3 MB -> ~1700cy;
// VALU ~2048 cy; LDS pipe ~2000 cy -> step ~2500-2900 cy.
// Plain per-iteration loads, v7-style (compiler scheduling achieves the
// roofline; v8's hand pipeline exposed latency and regressed 2x).
// Thread tid = half*256 + j: 4 gates of hidden j, K-half, both batches.
//   kcl 0..11 streamed from L2; kcl 12..15 LDS-resident (128 KB).
// ---------------------------------------------------------------------------
__global__ __launch_bounds__(512, 2)
void k_lstm(
    const __hip_bfloat16* __restrict__ xg,     // [2][B*T][1024] bf16
    const uint4* __restrict__ Wp,              // f16 packed [2][32][4][256]
    const int* __restrict__ seq_len,
    __hip_bfloat16* __restrict__ hcat)         // [B*T][512]
{
    int bp  = blockIdx.x & 31;       // batch pair
    int dir = blockIdx.x >> 5;
    int b0  = bp * 2, b1 = bp * 2 + 1;
    int tid = threadIdx.x;           // 0..511
    int j   = tid & 255;
    int half = tid >> 8;             // K-half this thread reduces

    __shared__ __align__(16) uint4 wlds[16 * 512];        // 131072 B
    __shared__ __align__(16) _Float16 hbf[2][2][HH];      // [batch][buf][HH] 2048 B
    __shared__ float pbuf[2][4][HH];                      // 8192 B

    const uint4* Wd = Wp + (size_t)dir * (32 * 4 * 256);

    // LDS-resident weights: kcl 12..15 (16 chunks = 128 KB)
#pragma unroll
    for (int kcl = 12; kcl < 16; ++kcl)
#pragma unroll
        for (int g = 0; g < 4; ++g)
            wlds[((kcl - 12) * 4 + g) * 512 + tid] =
                Wd[(((kcl + 16 * half) * 4 + g) * 256) + j];

    // stream base for this thread: chunk (kcl,g) at Ws[(kcl*4+g)*256]
    const uint4* Ws = Wd + (size_t)(16 * half) * 4 * 256 + j;

    if (half == 0) { hbf[0][0][j] = (_Float16)0.f; hbf[1][0][j] = (_Float16)0.f; }
    float c0 = 0.f, c1 = 0.f;
    int L0 = seq_len[b0], L1 = seq_len[b1];
    const __hip_bfloat16* xgb0 = xg + (size_t)dir * (size_t)(BB * TT * G4)
                                    + (size_t)b0 * TT * G4;
    const __hip_bfloat16* xgb1 = xg + (size_t)dir * (size_t)(BB * TT * G4)
                                    + (size_t)b1 * TT * G4;

    int tc0 = dir ? (L0 - 1) : 0;
    int tc1 = dir ? (L1 - 1) : 0;
    float xv00 = 0.f, xv01 = 0.f, xv02 = 0.f, xv03 = 0.f;
    float xv10 = 0.f, xv11 = 0.f, xv12 = 0.f, xv13 = 0.f;
    if (half == 0) {
        const __hip_bfloat16* xr0 = xgb0 + (size_t)tc0 * G4 + j;
        xv00 = __bfloat162float(xr0[0]);   xv01 = __bfloat162float(xr0[256]);
        xv02 = __bfloat162float(xr0[512]); xv03 = __bfloat162float(xr0[768]);
        const __hip_bfloat16* xr1 = xgb1 + (size_t)tc1 * G4 + j;
        xv10 = __bfloat162float(xr1[0]);   xv11 = __bfloat162float(xr1[256]);
        xv12 = __bfloat162float(xr1[512]); xv13 = __bfloat162float(xr1[768]);
    }
    __syncthreads();

#pragma unroll 1
    for (int t = 0; t < TT; ++t) {
        int cur = t & 1, nxt = cur ^ 1;
        int tn = t + 1;
        int tcn0 = dir ? ((tn < L0) ? (L0 - 1 - tn) : tn) : tn;
        int tcn1 = dir ? ((tn < L1) ? (L1 - 1 - tn) : tn) : tn;
        bool pf = (tn < TT);
        __hip_bfloat16 p00, p01, p02, p03, p10, p11, p12, p13;
        if (half == 0 && pf) {
            const __hip_bfloat16* xr0 = xgb0 + (size_t)tcn0 * G4 + j;
            p00 = xr0[0]; p01 = xr0[256]; p02 = xr0[512]; p03 = xr0[768];
            const __hip_bfloat16* xr1 = xgb1 + (size_t)tcn1 * G4 + j;
            p10 = xr1[0]; p11 = xr1[256]; p12 = xr1[512]; p13 = xr1[768];
        }

        const _Float16* h0 = &hbf[0][cur][half * 128];
        const _Float16* h1 = &hbf[1][cur][half * 128];
        float a0 = 0.f, a1 = 0.f, a2 = 0.f, a3 = 0.f;   // batch b0
        float d0 = 0.f, d1 = 0.f, d2 = 0.f, d3 = 0.f;   // batch b1

        // streamed weights, each chunk used for BOTH batches
#pragma unroll
        for (int kcl = 0; kcl < 12; ++kcl) {
            uint4 hv0 = *(const uint4*)(h0 + kcl * 8);  // wave-uniform bcast
            uint4 hv1 = *(const uint4*)(h1 + kcl * 8);
            uint4 w0 = Ws[(kcl * 4 + 0) * 256];
            uint4 w1 = Ws[(kcl * 4 + 1) * 256];
            uint4 w2 = Ws[(kcl * 4 + 2) * 256];
            uint4 w3 = Ws[(kcl * 4 + 3) * 256];
            a0 = dot8(a0, w0, hv0); d0 = dot8(d0, w0, hv1);
            a1 = dot8(a1, w1, hv0); d1 = dot8(d1, w1, hv1);
            a2 = dot8(a2, w2, hv0); d2 = dot8(d2, w2, hv1);
            a3 = dot8(a3, w3, hv0); d3 = dot8(d3, w3, hv1);
        }
        // LDS-resident weights
#pragma unroll
        for (int kcl = 12; kcl < 16; ++kcl) {
            uint4 hv0 = *(const uint4*)(h0 + kcl * 8);
            uint4 hv1 = *(const uint4*)(h1 + kcl * 8);
            int m0 = (kcl - 12) * 4;
            uint4 w0 = wlds[(m0 + 0) * 512 + tid];
            uint4 w1 = wlds[(m0 + 1) * 512 + tid];
            uint4 w2 = wlds[(m0 + 2) * 512 + tid];
            uint4 w3 = wlds[(m0 + 3) * 512 + tid];
            a0 = dot8(a0, w0, hv0); d0 = dot8(d0, w0, hv1);
            a1 = dot8(a1, w1, hv0); d1 = dot8(d1, w1, hv1);
            a2 = dot8(a2, w2, hv0); d2 = dot8(d2, w2, hv1);
            a3 = dot8(a3, w3, hv0); d3 = dot8(d3, w3, hv1);
        }

        if (half) {
            pbuf[0][0][j] = a0; pbuf[0][1][j] = a1;
            pbuf[0][2][j] = a2; pbuf[0][3][j] = a3;
            pbuf[1][0][j] = d0; pbuf[1][1][j] = d1;
            pbuf[1][2][j] = d2; pbuf[1][3][j] = d3;
        }
        __syncthreads();

        if (half == 0) {
            {
                float gi = a0 + pbuf[0][0][j] + xv00;
                float gf = a1 + pbuf[0][1][j] + xv01;
                float gg = a2 + pbuf[0][2][j] + xv02;
                float go = a3 + pbuf[0][3][j] + xv03;
                float i_ = sigf(gi), f_ = sigf(gf), G = tanh_s(gg), o_ = sigf(go);
                c0 = f_ * c0 + i_ * G;
                float h = o_ * tanh_s(c0);
                hbf[0][nxt][j] = (_Float16)h;
                hcat[((size_t)(b0 * TT + tc0)) * (2 * HH) + dir * HH + j] = __float2bfloat16(h);
            }
            {
                float gi = d0 + pbuf[1][0][j] + xv10;
                float gf = d1 + pbuf[1][1][j] + xv11;
                float gg = d2 + pbuf[1][2][j] + xv12;
                float go = d3 + pbuf[1][3][j] + xv13;
                float i_ = sigf(gi), f_ = sigf(gf), G = tanh_s(gg), o_ = sigf(go);
                c1 = f_ * c1 + i_ * G;
                float h = o_ * tanh_s(c1);
                hbf[1][nxt][j] = (_Float16)h;
                hcat[((size_t)(b1 * TT + tc1)) * (2 * HH) + dir * HH + j] = __float2bfloat16(h);
            }
            if (pf) {
                xv00 = __bfloat162float(p00); xv01 = __bfloat162float(p01);
                xv02 = __bfloat162float(p02); xv03 = __bfloat162float(p03);
                xv10 = __bfloat162float(p10); xv11 = __bfloat162float(p11);
                xv12 = __bfloat162float(p12); xv13 = __bfloat162float(p13);
            }
        }
        tc0 = tcn0; tc1 = tcn1;
        __syncthreads();
    }
}

// ---------------------------------------------------------------------------
// Kernel 3: feats = hcat @ fc_W^T + fc_b ; logits = log_softmax(feats)
// 4 rows per 256-thread block (one 64-lane wave-team per row).
// ---------------------------------------------------------------------------
__global__ __launch_bounds__(256) void k_fc(
    const __hip_bfloat16* __restrict__ hcat,
    const __hip_bfloat16* __restrict__ fcW,
    const float* __restrict__ fcb,
    float* __restrict__ logits)
{
    int team = threadIdx.x >> 6;   // 0..3
    int tid  = threadIdx.x & 63;
    int row  = blockIdx.x * 4 + team;
    __shared__ __align__(16) float hrow[4][2 * HH];
    __shared__ float fbuf[4][CC + 2];

    {
        uint4 v = *(const uint4*)(hcat + (size_t)row * (2 * HH) + tid * 8);
        float* d = &hrow[team][tid * 8];
        d[0] = bl16(v.x); d[1] = bh16(v.x);
        d[2] = bl16(v.y); d[3] = bh16(v.y);
        d[4] = bl16(v.z); d[5] = bh16(v.z);
        d[6] = bl16(v.w); d[7] = bh16(v.w);
    }
    __syncthreads();

    if (tid < CC) {
        float acc = fcb[tid];
        const uint4* wr = (const uint4*)(fcW + (size_t)tid * (2 * HH));
#pragma unroll 8
        for (int kc = 0; kc < 64; ++kc) {
            uint4 wv = wr[kc];
            float4 h0 = *(const float4*)&hrow[team][kc * 8];
            float4 h1 = *(const float4*)&hrow[team][kc * 8 + 4];
            acc = fmaf(bl16(wv.x), h0.x, acc); acc = fmaf(bh16(wv.x), h0.y, acc);
            acc = fmaf(bl16(wv.y), h0.z, acc); acc = fmaf(bh16(wv.y), h0.w, acc);
            acc = fmaf(bl16(wv.z), h1.x, acc); acc = fmaf(bh16(wv.z), h1.y, acc);
            acc = fmaf(bl16(wv.w), h1.z, acc); acc = fmaf(bh16(wv.w), h1.w, acc);
        }
        fbuf[team][tid] = acc;
    }
    __syncthreads();

    float m = -1e30f;
    for (int i = 0; i < CC; ++i) m = fmaxf(m, fbuf[team][i]);
    float s = 0.f;
    for (int i = 0; i < CC; ++i) s += __expf(fbuf[team][i] - m);
    float lns = __logf(s);
    if (tid < CC) logits[(size_t)row * CC + tid] = fbuf[team][tid] - m - lns;
}

// ---------------------------------------------------------------------------
// Kernel 4: CRF forward scan + gold score; per-batch loss -> loss_b[b]
// ---------------------------------------------------------------------------
__global__ __launch_bounds__(256) void k_crf(
    const float* __restrict__ logits,
    const int* __restrict__ target,
    const int* __restrict__ seq_len,
    const float* __restrict__ trans,
    const float* __restrict__ start_s,
    const float* __restrict__ end_s,
    float* __restrict__ loss_b)
{
    const float L2E = 1.4426950408889634f;
    const float LN2 = 0.6931471805599453f;
    int b = blockIdx.x;
    int tid = threadIdx.x;
    int q = tid >> 6;
    int j = tid & 63;
    bool act = (j < CC);
    int L = seq_len[b];
    const float* lg = logits + (size_t)b * TT * CC;

    __shared__ float alpha2[64];
    __shared__ float mpart[4][64];
    __shared__ float spart[4][64];
    __shared__ float red[256];
    __shared__ float nbuf[CC + 2];

    int i0 = q * 13;
    int icnt = min(13, CC - i0);
    float treg[13];
    if (act) {
#pragma unroll
        for (int s = 0; s < 13; ++s)
            if (s < icnt) treg[s] = L2E * trans[(i0 + s) * CC + j];
    }
    if (q == 0 && act) alpha2[j] = L2E * (lg[j] + start_s[j]);
    __syncthreads();

    float v[13];
    for (int t = 1; t < L; ++t) {
        float mq = -1e30f;
        if (act) {
#pragma unroll
            for (int s = 0; s < 13; ++s)
                if (s < icnt) { v[s] = alpha2[i0 + s] + treg[s]; mq = fmaxf(mq, v[s]); }
        }
        mpart[q][j] = mq;
        __syncthreads();
        float M = fmaxf(fmaxf(mpart[0][j], mpart[1][j]), fmaxf(mpart[2][j], mpart[3][j]));
        float sq = 0.f;
        if (act) {
#pragma unroll
            for (int s = 0; s < 13; ++s)
                if (s < icnt) sq += exp2f(v[s] - M);
        }
        spart[q][j] = sq;
        __syncthreads();
        if (q == 0 && act) {
            float S = spart[0][j] + spart[1][j] + spart[2][j] + spart[3][j];
            alpha2[j] = M + log2f(S) + L2E * lg[(size_t)t * CC + j];
        }
        __syncthreads();
    }

    if (q == 0 && act) nbuf[j] = alpha2[j] + L2E * end_s[j];

    float gp = 0.f;
    const int* tg = target + b * TT;
    for (int t = tid; t < TT; t += 256) {
        if (t < L) {
            int c = tg[t];
            gp += lg[(size_t)t * CC + c];
            if (t >= 1) gp += trans[tg[t - 1] * CC + c];
        }
    }
    red[tid] = gp;
    __syncthreads();

    if (tid == 0) {
        float m2 = -1e30f;
        for (int i = 0; i < CC; ++i) m2 = fmaxf(m2, nbuf[i]);
        float s2 = 0.f;
        for (int i = 0; i < CC; ++i) s2 += exp2f(nbuf[i] - m2);
        float norm_nat = (m2 + log2f(s2)) * LN2;
        float g = 0.f;
        for (int i = 0; i < 256; ++i) g += red[i];
        g += start_s[tg[0]] + end_s[tg[L - 1]];
        loss_b[b] = norm_nat - g;
    }
}

// Parallel final reduction (one wave)
__global__ void k_fin(const float* __restrict__ loss_b, float* __restrict__ out)
{
    int t = threadIdx.x;
    float v = loss_b[t];
#pragma unroll
    for (int o = 32; o > 0; o >>= 1) v += __shfl_down(v, o);
    if (t == 0) out[0] = v * (1.f / BB);
}

// ---------------------------------------------------------------------------
extern "C" void kernel_launch(void* const* d_in, const int* in_sizes, int n_in,
                              void* d_out, int out_size, void* d_ws, size_t ws_size,
                              hipStream_t stream)
{
    const int* words   = (const int*)d_in[0];
    const int* target  = (const int*)d_in[1];
    const int* seq_len = (const int*)d_in[2];
    const float* emb    = (const float*)d_in[3];
    const float* W_ih_f = (const float*)d_in[4];
    const float* W_hh_f = (const float*)d_in[5];
    const float* b_f    = (const float*)d_in[6];
    const float* W_ih_b = (const float*)d_in[7];
    const float* W_hh_b = (const float*)d_in[8];
    const float* b_b    = (const float*)d_in[9];
    const float* fc_W   = (const float*)d_in[10];
    const float* fc_b   = (const float*)d_in[11];
    const float* trans  = (const float*)d_in[12];
    const float* start_s= (const float*)d_in[13];
    const float* end_s  = (const float*)d_in[14];

    char* ws = (char*)d_ws;
    // workspace layout (bytes):
    //   xg     : 134217728                         @ 0
    //   hcat   :  33554432                         @ 134217728
    //   logits :   6553600                         @ 167772160
    //     (Wp f16 lstm pack, 1 MB, overlaps logits: consumed by k_lstm
    //      BEFORE k_fc writes logits)
    //   loss_b :       256                         @ 174325760
    //   wihall :    524288  (bf16 [2048][128])     @ 174326016
    //   fcw_bf :     51200                         @ 174850304
    __hip_bfloat16* xg     = (__hip_bfloat16*)ws;
    __hip_bfloat16* hcat   = (__hip_bfloat16*)(ws + 134217728);
    float*          logits = (float*)(ws + 167772160);
    uint4*          Wp     = (uint4*)(ws + 167772160);
    float*          loss_b = (float*)(ws + 174325760);
    __hip_bfloat16* wihall = (__hip_bfloat16*)(ws + 174326016);
    __hip_bfloat16* fcw_bf = (__hip_bfloat16*)(ws + 174850304);

    k_cvt<<<64,  256, 0, stream>>>(W_ih_f, wihall,          131072);
    k_cvt<<<64,  256, 0, stream>>>(W_ih_b, wihall + 131072, 131072);
    k_cvt<<<13,  256, 0, stream>>>(fc_W,   fcw_bf,          25600);
    k_pack<<<256, 256, 0, stream>>>(W_hh_f, W_hh_b, Wp);

    k_xg  <<<512, 256, 0, stream>>>(words, emb, wihall, b_f, b_b, xg);
    k_lstm<<<64, 512, 0, stream>>>(xg, Wp, seq_len, hcat);
    k_fc  <<<8192, 256, 0, stream>>>(hcat, fcw_bf, fc_b, logits);
    k_crf <<<64, 256, 0, stream>>>(logits, target, seq_len, trans, start_s, end_s, loss_b);
    k_fin <<<1, 64, 0, stream>>>(loss_b, (float*)d_out);
}

// Round 6
// 2081.354 us; speedup vs baseline: 1.2535x; 1.1513x over previous
//
#include <hip/hip_runtime.h>
#include <hip/hip_bf16.h>

// Problem constants
#define BB 64
#define TT 512
#define DD 128
#define HH 256
#define G4 1024   // 4*H
#define CC 50

typedef __bf16 bf16x8 __attribute__((ext_vector_type(8)));
typedef float  f32x4  __attribute__((ext_vector_type(4)));
typedef _Float16 h16x2 __attribute__((ext_vector_type(2)));

#if defined(__has_builtin)
#if __has_builtin(__builtin_amdgcn_fdot2)
#define HAS_FDOT2 1
#endif
#endif

__device__ __forceinline__ float bl16(unsigned u) { return __uint_as_float(u << 16); }
__device__ __forceinline__ float bh16(unsigned u) { return __uint_as_float(u & 0xffff0000u); }

__device__ __forceinline__ float sigf(float x) {
    return 1.f / (1.f + __expf(-x));
}
__device__ __forceinline__ float tanh_s(float x) {
    float ax = fabsf(x);
    float e = __expf(-2.f * ax);
    float r = (1.f - e) / (1.f + e);
    return copysignf(r, x);
}

// 8-element f16 dot product chunk, f32 accumulate
__device__ __forceinline__ float dot8(float acc, uint4 w, uint4 h) {
#ifdef HAS_FDOT2
    acc = __builtin_amdgcn_fdot2(__builtin_bit_cast(h16x2, w.x),
                                 __builtin_bit_cast(h16x2, h.x), acc, false);
    acc = __builtin_amdgcn_fdot2(__builtin_bit_cast(h16x2, w.y),
                                 __builtin_bit_cast(h16x2, h.y), acc, false);
    acc = __builtin_amdgcn_fdot2(__builtin_bit_cast(h16x2, w.z),
                                 __builtin_bit_cast(h16x2, h.z), acc, false);
    acc = __builtin_amdgcn_fdot2(__builtin_bit_cast(h16x2, w.w),
                                 __builtin_bit_cast(h16x2, h.w), acc, false);
#else
    {
        h16x2 a = __builtin_bit_cast(h16x2, w.x), b = __builtin_bit_cast(h16x2, h.x);
        acc = fmaf((float)a.x, (float)b.x, acc); acc = fmaf((float)a.y, (float)b.y, acc);
        a = __builtin_bit_cast(h16x2, w.y); b = __builtin_bit_cast(h16x2, h.y);
        acc = fmaf((float)a.x, (float)b.x, acc); acc = fmaf((float)a.y, (float)b.y, acc);
        a = __builtin_bit_cast(h16x2, w.z); b = __builtin_bit_cast(h16x2, h.z);
        acc = fmaf((float)a.x, (float)b.x, acc); acc = fmaf((float)a.y, (float)b.y, acc);
        a = __builtin_bit_cast(h16x2, w.w); b = __builtin_bit_cast(h16x2, h.w);
        acc = fmaf((float)a.x, (float)b.x, acc); acc = fmaf((float)a.y, (float)b.y, acc);
    }
#endif
    return acc;
}

// ---------------------------------------------------------------------------
// Kernel 0: f32 -> bf16 conversion (8 elements/thread)
// ---------------------------------------------------------------------------
__global__ __launch_bounds__(256) void k_cvt(
    const float* __restrict__ src, __hip_bfloat16* __restrict__ dst, int n)
{
    int i = (blockIdx.x * 256 + threadIdx.x) * 8;
    if (i + 8 <= n) {
        float4 a = *(const float4*)(src + i);
        float4 b = *(const float4*)(src + i + 4);
        __hip_bfloat16 o[8];
        o[0] = __float2bfloat16(a.x); o[1] = __float2bfloat16(a.y);
        o[2] = __float2bfloat16(a.z); o[3] = __float2bfloat16(a.w);
        o[4] = __float2bfloat16(b.x); o[5] = __float2bfloat16(b.y);
        o[6] = __float2bfloat16(b.z); o[7] = __float2bfloat16(b.w);
        *(uint4*)(dst + i) = *(const uint4*)o;
    }
}

// ---------------------------------------------------------------------------
// Kernel 0b: pack W_hh (f32 [1024][256]) -> f16.
// Wp[((dir*32 + kc)*4 + g)*256 + j] = 8 f16 of row (g*256 + j), k in
// [8kc, 8kc+8).  k_lstm thread tid = half*256+j consumes kc = kcl + 16*half.
// ---------------------------------------------------------------------------
__global__ __launch_bounds__(256) void k_pack(
    const float* __restrict__ Wf, const float* __restrict__ Wb,
    uint4* __restrict__ Wp)
{
    int blk = blockIdx.x;            // 256 blocks = dir*128 + kc*4 + g
    int g   = blk & 3;
    int kc  = (blk >> 2) & 31;
    int dir = blk >> 7;
    int j = threadIdx.x;
    int row = g * 256 + j;
    const float* src = (dir ? Wb : Wf) + (size_t)row * 256 + kc * 8;
    float4 a = *(const float4*)src;
    float4 b = *(const float4*)(src + 4);
    _Float16 o[8];
    o[0] = (_Float16)a.x; o[1] = (_Float16)a.y;
    o[2] = (_Float16)a.z; o[3] = (_Float16)a.w;
    o[4] = (_Float16)b.x; o[5] = (_Float16)b.y;
    o[6] = (_Float16)b.z; o[7] = (_Float16)b.w;
    Wp[((size_t)(dir * 32 + kc) * 4 + g) * 256 + j] = *(const uint4*)o;
}

// ---------------------------------------------------------------------------
// Kernel 1: xg = emb[words] @ W_ih^T + b, LDS-staged MFMA GEMM (unchanged).
// ---------------------------------------------------------------------------
__global__ __launch_bounds__(256, 2) void k_xg(
    const int* __restrict__ words,
    const float* __restrict__ embf,           // f32 [50000][128]
    const __hip_bfloat16* __restrict__ Wih,   // bf16 [2048][128] (fwd|bwd)
    const float* __restrict__ bfv, const float* __restrict__ bbv,
    __hip_bfloat16* __restrict__ xg)
{
    __shared__ __align__(16) __hip_bfloat16 A[64][136];
    int tid = threadIdx.x;
    int bt0 = blockIdx.x * 64;

    {
        int r = tid >> 2;
        int c0 = (tid & 3) * 32;
        int word = words[bt0 + r];
        const float* src = embf + (size_t)word * DD + c0;
#pragma unroll
        for (int i = 0; i < 8; ++i) {
            float4 v = *(const float4*)(src + i * 4);
            __hip_bfloat16 o[4] = {__float2bfloat16(v.x), __float2bfloat16(v.y),
                                   __float2bfloat16(v.z), __float2bfloat16(v.w)};
            *(uint2*)&A[r][c0 + i * 4] = *(const uint2*)o;
        }
    }
    __syncthreads();

    int wave = tid >> 6, lane = tid & 63;
    int m = lane & 15, quad = lane >> 4;

    bf16x8 afr[4][4];
#pragma unroll
    for (int ms = 0; ms < 4; ++ms)
#pragma unroll
        for (int kf = 0; kf < 4; ++kf)
            afr[ms][kf] = *(const bf16x8*)&A[ms * 16 + m][quad * 8 + kf * 32];

#pragma unroll 1
    for (int i = 0; i < 32; ++i) {
        int nt = wave * 32 + i;
        int gate_g = nt * 16 + m;            // 0..2047
        int dir = gate_g >> 10;
        int gate = gate_g & 1023;
        const __hip_bfloat16* brow = Wih + (size_t)gate_g * DD + quad * 8;
        bf16x8 bfr[4];
#pragma unroll
        for (int kf = 0; kf < 4; ++kf) bfr[kf] = *(const bf16x8*)(brow + kf * 32);
        float bv = dir ? bbv[gate] : bfv[gate];
        size_t dbase = (size_t)dir * (size_t)(BB * TT * G4);

#pragma unroll
        for (int ms = 0; ms < 4; ++ms) {
            f32x4 acc = {0.f, 0.f, 0.f, 0.f};
#pragma unroll
            for (int kf = 0; kf < 4; ++kf)
                acc = __builtin_amdgcn_mfma_f32_16x16x32_bf16(afr[ms][kf], bfr[kf], acc, 0, 0, 0);
#pragma unroll
            for (int r = 0; r < 4; ++r) {
                int btrow = bt0 + ms * 16 + quad * 4 + r;
                xg[dbase + (size_t)btrow * G4 + gate] = __float2bfloat16(acc[r] + bv);
            }
        }
    }
}

// ---------------------------------------------------------------------------
// Kernel 2: LSTM recurrence v10.
// Model (r5): binding constraint = streamed weight bytes/CU/step vs the
// per-CU share of XCD-L2 BW (~112 B/cy at 16 blocks/XCD). Keep 128 blocks
// (v9's 64-block pairing starved CUs). Residency mix:
//   kcl 0..3   : 16 chunks, 64 VGPR, reg-held w/ per-iter pin (SMALL ask --
//                total pressure ~200 < 256 cap; rounds 1-3 asked 192-416 and
//                the RA refused, 64 never tested)
//   kcl 4..11  : streamed 262 KB/step in two 4-kc groups; group-1 latency
//                hides under held-dots + LDS-dots, group-2 under group-1 dots
//   kcl 12..15 : 16 chunks LDS (128 KB; LDS residency is maxed)
// ---------------------------------------------------------------------------
__global__ __launch_bounds__(512, 2)
void k_lstm(
    const __hip_bfloat16* __restrict__ xg,     // [2][B*T][1024] bf16
    const uint4* __restrict__ Wp,              // f16 packed [2][32][4][256]
    const int* __restrict__ seq_len,
    __hip_bfloat16* __restrict__ hcat)         // [B*T][512]
{
    int b = blockIdx.x & 63;
    int dir = blockIdx.x >> 6;
    int tid = threadIdx.x;      // 0..511
    int j   = tid & 255;
    int half = tid >> 8;        // K-half this thread reduces

    __shared__ __align__(16) uint4 wlds[16 * 512];        // 131072 B
    __shared__ __align__(16) _Float16 hbf[2][HH];         //   1024 B
    __shared__ float pbuf[4][HH];                         //   4096 B

    const uint4* Wd = Wp + (size_t)dir * (32 * 4 * 256);
    // chunk (kcl, g) of this thread lives at Ws[(kcl*4 + g)*256]
    const uint4* Ws = Wd + (size_t)(16 * half) * 4 * 256 + j;

    // reg-held weights: kcl 0..3 (16 chunks = 64 VGPRs)
    uint4 wh[4][4];
#pragma unroll
    for (int kcl = 0; kcl < 4; ++kcl)
#pragma unroll
        for (int g = 0; g < 4; ++g)
            wh[kcl][g] = Ws[(kcl * 4 + g) * 256];

    // LDS-resident weights: kcl 12..15
#pragma unroll
    for (int kcl = 12; kcl < 16; ++kcl)
#pragma unroll
        for (int g = 0; g < 4; ++g)
            wlds[((kcl - 12) * 4 + g) * 512 + tid] = Ws[(kcl * 4 + g) * 256];

    if (half == 0) hbf[0][j] = (_Float16)0.f;
    float c = 0.f;
    int L = seq_len[b];
    const __hip_bfloat16* xgb = xg + (size_t)dir * (size_t)(BB * TT * G4)
                                   + (size_t)b * TT * G4;

    int tc = dir ? (L - 1) : 0;
    float xv0 = 0.f, xv1 = 0.f, xv2 = 0.f, xv3 = 0.f;
    if (half == 0) {
        const __hip_bfloat16* xr = xgb + (size_t)tc * G4 + j;
        xv0 = __bfloat162float(xr[0]);   xv1 = __bfloat162float(xr[256]);
        xv2 = __bfloat162float(xr[512]); xv3 = __bfloat162float(xr[768]);
    }
    __syncthreads();

#pragma unroll 1
    for (int t = 0; t < TT; ++t) {
        // loop-carried pin: forbids remat of the 16 held chunks (64 VGPR ask)
#pragma unroll
        for (int kcl = 0; kcl < 4; ++kcl)
#pragma unroll
            for (int g = 0; g < 4; ++g)
                asm volatile("" : "+v"(wh[kcl][g].x), "+v"(wh[kcl][g].y),
                                  "+v"(wh[kcl][g].z), "+v"(wh[kcl][g].w));

        int cur = t & 1, nxt = cur ^ 1;
        int tn = t + 1;
        int tcn = dir ? ((tn < L) ? (L - 1 - tn) : tn) : tn;
        bool pf = (tn < TT);
        __hip_bfloat16 p0, p1, p2, p3;
        if (half == 0 && pf) {
            const __hip_bfloat16* xr = xgb + (size_t)tcn * G4 + j;
            p0 = xr[0]; p1 = xr[256]; p2 = xr[512]; p3 = xr[768];
        }

        // launder offset so LDS weight reads can't be hoisted out of t-loop
        unsigned off = 0;
        asm volatile("" : "+v"(off));

        const _Float16* hrow = &hbf[cur][half * 128];
        float a0 = 0.f, a1 = 0.f, a2 = 0.f, a3 = 0.f;

        // --- issue stream group 1 (kcl 4..7), latency hidden by next phases
        uint4 s1[4][4];
#pragma unroll
        for (int q = 0; q < 4; ++q)
#pragma unroll
            for (int g = 0; g < 4; ++g)
                s1[q][g] = Ws[((q + 4) * 4 + g) * 256];

        // --- held dots (pure VALU)
#pragma unroll
        for (int kcl = 0; kcl < 4; ++kcl) {
            uint4 hv = *(const uint4*)(hrow + kcl * 8);
            a0 = dot8(a0, wh[kcl][0], hv);
            a1 = dot8(a1, wh[kcl][1], hv);
            a2 = dot8(a2, wh[kcl][2], hv);
            a3 = dot8(a3, wh[kcl][3], hv);
        }

        // --- LDS-resident dots (LDS pipe)
#pragma unroll
        for (int kcl = 12; kcl < 16; ++kcl) {
            uint4 hv = *(const uint4*)(hrow + kcl * 8);
            int m0 = (kcl - 12) * 4;
            a0 = dot8(a0, wlds[(m0 + 0) * 512 + tid + off], hv);
            a1 = dot8(a1, wlds[(m0 + 1) * 512 + tid + off], hv);
            a2 = dot8(a2, wlds[(m0 + 2) * 512 + tid + off], hv);
            a3 = dot8(a3, wlds[(m0 + 3) * 512 + tid + off], hv);
        }

        // --- issue stream group 2 (kcl 8..11), then consume group 1
        uint4 s2[4][4];
#pragma unroll
        for (int q = 0; q < 4; ++q)
#pragma unroll
            for (int g = 0; g < 4; ++g)
                s2[q][g] = Ws[((q + 8) * 4 + g) * 256];

#pragma unroll
        for (int q = 0; q < 4; ++q) {
            uint4 hv = *(const uint4*)(hrow + (q + 4) * 8);
            a0 = dot8(a0, s1[q][0], hv);
            a1 = dot8(a1, s1[q][1], hv);
            a2 = dot8(a2, s1[q][2], hv);
            a3 = dot8(a3, s1[q][3], hv);
        }
#pragma unroll
        for (int q = 0; q < 4; ++q) {
            uint4 hv = *(const uint4*)(hrow + (q + 8) * 8);
            a0 = dot8(a0, s2[q][0], hv);
            a1 = dot8(a1, s2[q][1], hv);
            a2 = dot8(a2, s2[q][2], hv);
            a3 = dot8(a3, s2[q][3], hv);
        }

        if (half) {
            pbuf[0][j] = a0; pbuf[1][j] = a1;
            pbuf[2][j] = a2; pbuf[3][j] = a3;
        }
        __syncthreads();

        if (half == 0) {
            float gi = a0 + pbuf[0][j] + xv0;
            float gf = a1 + pbuf[1][j] + xv1;
            float gg = a2 + pbuf[2][j] + xv2;
            float go = a3 + pbuf[3][j] + xv3;
            float i_ = sigf(gi), f_ = sigf(gf), G = tanh_s(gg), o_ = sigf(go);
            c = f_ * c + i_ * G;
            float h = o_ * tanh_s(c);
            hbf[nxt][j] = (_Float16)h;
            hcat[((size_t)(b * TT + tc)) * (2 * HH) + dir * HH + j] = __float2bfloat16(h);
            if (pf) {
                xv0 = __bfloat162float(p0); xv1 = __bfloat162float(p1);
                xv2 = __bfloat162float(p2); xv3 = __bfloat162float(p3);
            }
        }
        tc = tcn;
        __syncthreads();
    }
}

// ---------------------------------------------------------------------------
// Kernel 3: feats = hcat @ fc_W^T + fc_b ; logits = log_softmax(feats)
// 4 rows per 256-thread block (one 64-lane wave-team per row).
// ---------------------------------------------------------------------------
__global__ __launch_bounds__(256) void k_fc(
    const __hip_bfloat16* __restrict__ hcat,
    const __hip_bfloat16* __restrict__ fcW,
    const float* __restrict__ fcb,
    float* __restrict__ logits)
{
    int team = threadIdx.x >> 6;   // 0..3
    int tid  = threadIdx.x & 63;
    int row  = blockIdx.x * 4 + team;
    __shared__ __align__(16) float hrow[4][2 * HH];
    __shared__ float fbuf[4][CC + 2];

    {
        uint4 v = *(const uint4*)(hcat + (size_t)row * (2 * HH) + tid * 8);
        float* d = &hrow[team][tid * 8];
        d[0] = bl16(v.x); d[1] = bh16(v.x);
        d[2] = bl16(v.y); d[3] = bh16(v.y);
        d[4] = bl16(v.z); d[5] = bh16(v.z);
        d[6] = bl16(v.w); d[7] = bh16(v.w);
    }
    __syncthreads();

    if (tid < CC) {
        float acc = fcb[tid];
        const uint4* wr = (const uint4*)(fcW + (size_t)tid * (2 * HH));
#pragma unroll 8
        for (int kc = 0; kc < 64; ++kc) {
            uint4 wv = wr[kc];
            float4 h0 = *(const float4*)&hrow[team][kc * 8];
            float4 h1 = *(const float4*)&hrow[team][kc * 8 + 4];
            acc = fmaf(bl16(wv.x), h0.x, acc); acc = fmaf(bh16(wv.x), h0.y, acc);
            acc = fmaf(bl16(wv.y), h0.z, acc); acc = fmaf(bh16(wv.y), h0.w, acc);
            acc = fmaf(bl16(wv.z), h1.x, acc); acc = fmaf(bh16(wv.z), h1.y, acc);
            acc = fmaf(bl16(wv.w), h1.z, acc); acc = fmaf(bh16(wv.w), h1.w, acc);
        }
        fbuf[team][tid] = acc;
    }
    __syncthreads();

    float m = -1e30f;
    for (int i = 0; i < CC; ++i) m = fmaxf(m, fbuf[team][i]);
    float s = 0.f;
    for (int i = 0; i < CC; ++i) s += __expf(fbuf[team][i] - m);
    float lns = __logf(s);
    if (tid < CC) logits[(size_t)row * CC + tid] = fbuf[team][tid] - m - lns;
}

// ---------------------------------------------------------------------------
// Kernel 4: CRF forward scan + gold score; per-batch loss -> loss_b[b]
// v2: lg[t] row prefetched one iteration ahead (the load was on the serial
// critical path of the 512-iteration scan).
// ---------------------------------------------------------------------------
__global__ __launch_bounds__(256) void k_crf(
    const float* __restrict__ logits,
    const int* __restrict__ target,
    const int* __restrict__ seq_len,
    const float* __restrict__ trans,
    const float* __restrict__ start_s,
    const float* __restrict__ end_s,
    float* __restrict__ loss_b)
{
    const float L2E = 1.4426950408889634f;
    const float LN2 = 0.6931471805599453f;
    int b = blockIdx.x;
    int tid = threadIdx.x;
    int q = tid >> 6;
    int j = tid & 63;
    bool act = (j < CC);
    int L = seq_len[b];
    const float* lg = logits + (size_t)b * TT * CC;

    __shared__ float alpha2[64];
    __shared__ float mpart[4][64];
    __shared__ float spart[4][64];
    __shared__ float red[256];
    __shared__ float nbuf[CC + 2];

    int i0 = q * 13;
    int icnt = min(13, CC - i0);
    float treg[13];
    if (act) {
#pragma unroll
        for (int s = 0; s < 13; ++s)
            if (s < icnt) treg[s] = L2E * trans[(i0 + s) * CC + j];
    }
    if (q == 0 && act) alpha2[j] = L2E * (lg[j] + start_s[j]);
    __syncthreads();

    float v[13];
    float lgreg = 0.f;
    if (q == 0 && act) lgreg = lg[CC + j];          // row t=1
    for (int t = 1; t < L; ++t) {
        float lgnext = 0.f;
        if (q == 0 && act && (t + 1) < L)
            lgnext = lg[(size_t)(t + 1) * CC + j];  // prefetch next row

        float mq = -1e30f;
        if (act) {
#pragma unroll
            for (int s = 0; s < 13; ++s)
                if (s < icnt) { v[s] = alpha2[i0 + s] + treg[s]; mq = fmaxf(mq, v[s]); }
        }
        mpart[q][j] = mq;
        __syncthreads();
        float M = fmaxf(fmaxf(mpart[0][j], mpart[1][j]), fmaxf(mpart[2][j], mpart[3][j]));
        float sq = 0.f;
        if (act) {
#pragma unroll
            for (int s = 0; s < 13; ++s)
                if (s < icnt) sq += exp2f(v[s] - M);
        }
        spart[q][j] = sq;
        __syncthreads();
        if (q == 0 && act) {
            float S = spart[0][j] + spart[1][j] + spart[2][j] + spart[3][j];
            alpha2[j] = M + log2f(S) + L2E * lgreg;
        }
        lgreg = lgnext;
        __syncthreads();
    }

    if (q == 0 && act) nbuf[j] = alpha2[j] + L2E * end_s[j];

    float gp = 0.f;
    const int* tg = target + b * TT;
    for (int t = tid; t < TT; t += 256) {
        if (t < L) {
            int c = tg[t];
            gp += lg[(size_t)t * CC + c];
            if (t >= 1) gp += trans[tg[t - 1] * CC + c];
        }
    }
    red[tid] = gp;
    __syncthreads();

    if (tid == 0) {
        float m2 = -1e30f;
        for (int i = 0; i < CC; ++i) m2 = fmaxf(m2, nbuf[i]);
        float s2 = 0.f;
        for (int i = 0; i < CC; ++i) s2 += exp2f(nbuf[i] - m2);
        float norm_nat = (m2 + log2f(s2)) * LN2;
        float g = 0.f;
        for (int i = 0; i < 256; ++i) g += red[i];
        g += start_s[tg[0]] + end_s[tg[L - 1]];
        loss_b[b] = norm_nat - g;
    }
}

// Parallel final reduction (one wave)
__global__ void k_fin(const float* __restrict__ loss_b, float* __restrict__ out)
{
    int t = threadIdx.x;
    float v = loss_b[t];
#pragma unroll
    for (int o = 32; o > 0; o >>= 1) v += __shfl_down(v, o);
    if (t == 0) out[0] = v * (1.f / BB);
}

// ---------------------------------------------------------------------------
extern "C" void kernel_launch(void* const* d_in, const int* in_sizes, int n_in,
                              void* d_out, int out_size, void* d_ws, size_t ws_size,
                              hipStream_t stream)
{
    const int* words   = (const int*)d_in[0];
    const int* target  = (const int*)d_in[1];
    const int* seq_len = (const int*)d_in[2];
    const float* emb    = (const float*)d_in[3];
    const float* W_ih_f = (const float*)d_in[4];
    const float* W_hh_f = (const float*)d_in[5];
    const float* b_f    = (const float*)d_in[6];
    const float* W_ih_b = (const float*)d_in[7];
    const float* W_hh_b = (const float*)d_in[8];
    const float* b_b    = (const float*)d_in[9];
    const float* fc_W   = (const float*)d_in[10];
    const float* fc_b   = (const float*)d_in[11];
    const float* trans  = (const float*)d_in[12];
    const float* start_s= (const float*)d_in[13];
    const float* end_s  = (const float*)d_in[14];

    char* ws = (char*)d_ws;
    // workspace layout (bytes):
    //   xg     : 134217728                         @ 0
    //   hcat   :  33554432                         @ 134217728
    //   logits :   6553600                         @ 167772160
    //     (Wp f16 lstm pack, 1 MB, overlaps logits: consumed by k_lstm
    //      BEFORE k_fc writes logits)
    //   loss_b :       256                         @ 174325760
    //   wihall :    524288  (bf16 [2048][128])     @ 174326016
    //   fcw_bf :     51200                         @ 174850304
    __hip_bfloat16* xg     = (__hip_bfloat16*)ws;
    __hip_bfloat16* hcat   = (__hip_bfloat16*)(ws + 134217728);
    float*          logits = (float*)(ws + 167772160);
    uint4*          Wp     = (uint4*)(ws + 167772160);
    float*          loss_b = (float*)(ws + 174325760);
    __hip_bfloat16* wihall = (__hip_bfloat16*)(ws + 174326016);
    __hip_bfloat16* fcw_bf = (__hip_bfloat16*)(ws + 174850304);

    k_cvt<<<64,  256, 0, stream>>>(W_ih_f, wihall,          131072);
    k_cvt<<<64,  256, 0, stream>>>(W_ih_b, wihall + 131072, 131072);
    k_cvt<<<13,  256, 0, stream>>>(fc_W,   fcw_bf,          25600);
    k_pack<<<256, 256, 0, stream>>>(W_hh_f, W_hh_b, Wp);

    k_xg  <<<512, 256, 0, stream>>>(words, emb, wihall, b_f, b_b, xg);
    k_lstm<<<128, 512, 0, stream>>>(xg, Wp, seq_len, hcat);
    k_fc  <<<8192, 256, 0, stream>>>(hcat, fcw_bf, fc_b, logits);
    k_crf <<<64, 256, 0, stream>>>(logits, target, seq_len, trans, start_s, end_s, loss_b);
    k_fin <<<1, 64, 0, stream>>>(loss_b, (float*)d_out);
}

// Round 7
// 2001.219 us; speedup vs baseline: 1.3037x; 1.0400x over previous
//
#include <hip/hip_runtime.h>
#include <hip/hip_bf16.h>

// Problem constants
#define BB 64
#define TT 512
#define DD 128
#define HH 256
#define G4 1024   // 4*H
#define CC 50

typedef __bf16 bf16x8 __attribute__((ext_vector_type(8)));
typedef float  f32x4  __attribute__((ext_vector_type(4)));
typedef _Float16 h16x2 __attribute__((ext_vector_type(2)));

#if defined(__has_builtin)
#if __has_builtin(__builtin_amdgcn_fdot2)
#define HAS_FDOT2 1
#endif
#endif

__device__ __forceinline__ float bl16(unsigned u) { return __uint_as_float(u << 16); }
__device__ __forceinline__ float bh16(unsigned u) { return __uint_as_float(u & 0xffff0000u); }

__device__ __forceinline__ float sigf(float x) {
    return 1.f / (1.f + __expf(-x));
}
__device__ __forceinline__ float tanh_s(float x) {
    float ax = fabsf(x);
    float e = __expf(-2.f * ax);
    float r = (1.f - e) / (1.f + e);
    return copysignf(r, x);
}

// 8-element f16 dot product chunk, f32 accumulate
__device__ __forceinline__ float dot8(float acc, uint4 w, uint4 h) {
#ifdef HAS_FDOT2
    acc = __builtin_amdgcn_fdot2(__builtin_bit_cast(h16x2, w.x),
                                 __builtin_bit_cast(h16x2, h.x), acc, false);
    acc = __builtin_amdgcn_fdot2(__builtin_bit_cast(h16x2, w.y),
                                 __builtin_bit_cast(h16x2, h.y), acc, false);
    acc = __builtin_amdgcn_fdot2(__builtin_bit_cast(h16x2, w.z),
                                 __builtin_bit_cast(h16x2, h.z), acc, false);
    acc = __builtin_amdgcn_fdot2(__builtin_bit_cast(h16x2, w.w),
                                 __builtin_bit_cast(h16x2, h.w), acc, false);
#else
    {
        h16x2 a = __builtin_bit_cast(h16x2, w.x), b = __builtin_bit_cast(h16x2, h.x);
        acc = fmaf((float)a.x, (float)b.x, acc); acc = fmaf((float)a.y, (float)b.y, acc);
        a = __builtin_bit_cast(h16x2, w.y); b = __builtin_bit_cast(h16x2, h.y);
        acc = fmaf((float)a.x, (float)b.x, acc); acc = fmaf((float)a.y, (float)b.y, acc);
        a = __builtin_bit_cast(h16x2, w.z); b = __builtin_bit_cast(h16x2, h.z);
        acc = fmaf((float)a.x, (float)b.x, acc); acc = fmaf((float)a.y, (float)b.y, acc);
        a = __builtin_bit_cast(h16x2, w.w); b = __builtin_bit_cast(h16x2, h.w);
        acc = fmaf((float)a.x, (float)b.x, acc); acc = fmaf((float)a.y, (float)b.y, acc);
    }
#endif
    return acc;
}

// ---------------------------------------------------------------------------
// Kernel 0: f32 -> bf16 conversion (8 elements/thread)
// ---------------------------------------------------------------------------
__global__ __launch_bounds__(256) void k_cvt(
    const float* __restrict__ src, __hip_bfloat16* __restrict__ dst, int n)
{
    int i = (blockIdx.x * 256 + threadIdx.x) * 8;
    if (i + 8 <= n) {
        float4 a = *(const float4*)(src + i);
        float4 b = *(const float4*)(src + i + 4);
        __hip_bfloat16 o[8];
        o[0] = __float2bfloat16(a.x); o[1] = __float2bfloat16(a.y);
        o[2] = __float2bfloat16(a.z); o[3] = __float2bfloat16(a.w);
        o[4] = __float2bfloat16(b.x); o[5] = __float2bfloat16(b.y);
        o[6] = __float2bfloat16(b.z); o[7] = __float2bfloat16(b.w);
        *(uint4*)(dst + i) = *(const uint4*)o;
    }
}

// ---------------------------------------------------------------------------
// Kernel 0b: pack W_hh (f32 [1024][256]) -> f16.
// Wp[((dir*32 + kc)*4 + g)*256 + j] = 8 f16 of row (g*256 + j), k in
// [8kc, 8kc+8).  k_lstm thread tid = half*256+j consumes kc = kcl + 16*half.
// ---------------------------------------------------------------------------
__global__ __launch_bounds__(256) void k_pack(
    const float* __restrict__ Wf, const float* __restrict__ Wb,
    uint4* __restrict__ Wp)
{
    int blk = blockIdx.x;            // 256 blocks = dir*128 + kc*4 + g
    int g   = blk & 3;
    int kc  = (blk >> 2) & 31;
    int dir = blk >> 7;
    int j = threadIdx.x;
    int row = g * 256 + j;
    const float* src = (dir ? Wb : Wf) + (size_t)row * 256 + kc * 8;
    float4 a = *(const float4*)src;
    float4 b = *(const float4*)(src + 4);
    _Float16 o[8];
    o[0] = (_Float16)a.x; o[1] = (_Float16)a.y;
    o[2] = (_Float16)a.z; o[3] = (_Float16)a.w;
    o[4] = (_Float16)b.x; o[5] = (_Float16)b.y;
    o[6] = (_Float16)b.z; o[7] = (_Float16)b.w;
    Wp[((size_t)(dir * 32 + kc) * 4 + g) * 256 + j] = *(const uint4*)o;
}

// ---------------------------------------------------------------------------
// Kernel 1: xg = emb[words] @ W_ih^T + b, LDS-staged MFMA GEMM (unchanged).
// ---------------------------------------------------------------------------
__global__ __launch_bounds__(256, 2) void k_xg(
    const int* __restrict__ words,
    const float* __restrict__ embf,           // f32 [50000][128]
    const __hip_bfloat16* __restrict__ Wih,   // bf16 [2048][128] (fwd|bwd)
    const float* __restrict__ bfv, const float* __restrict__ bbv,
    __hip_bfloat16* __restrict__ xg)
{
    __shared__ __align__(16) __hip_bfloat16 A[64][136];
    int tid = threadIdx.x;
    int bt0 = blockIdx.x * 64;

    {
        int r = tid >> 2;
        int c0 = (tid & 3) * 32;
        int word = words[bt0 + r];
        const float* src = embf + (size_t)word * DD + c0;
#pragma unroll
        for (int i = 0; i < 8; ++i) {
            float4 v = *(const float4*)(src + i * 4);
            __hip_bfloat16 o[4] = {__float2bfloat16(v.x), __float2bfloat16(v.y),
                                   __float2bfloat16(v.z), __float2bfloat16(v.w)};
            *(uint2*)&A[r][c0 + i * 4] = *(const uint2*)o;
        }
    }
    __syncthreads();

    int wave = tid >> 6, lane = tid & 63;
    int m = lane & 15, quad = lane >> 4;

    bf16x8 afr[4][4];
#pragma unroll
    for (int ms = 0; ms < 4; ++ms)
#pragma unroll
        for (int kf = 0; kf < 4; ++kf)
            afr[ms][kf] = *(const bf16x8*)&A[ms * 16 + m][quad * 8 + kf * 32];

#pragma unroll 1
    for (int i = 0; i < 32; ++i) {
        int nt = wave * 32 + i;
        int gate_g = nt * 16 + m;            // 0..2047
        int dir = gate_g >> 10;
        int gate = gate_g & 1023;
        const __hip_bfloat16* brow = Wih + (size_t)gate_g * DD + quad * 8;
        bf16x8 bfr[4];
#pragma unroll
        for (int kf = 0; kf < 4; ++kf) bfr[kf] = *(const bf16x8*)(brow + kf * 32);
        float bv = dir ? bbv[gate] : bfv[gate];
        size_t dbase = (size_t)dir * (size_t)(BB * TT * G4);

#pragma unroll
        for (int ms = 0; ms < 4; ++ms) {
            f32x4 acc = {0.f, 0.f, 0.f, 0.f};
#pragma unroll
            for (int kf = 0; kf < 4; ++kf)
                acc = __builtin_amdgcn_mfma_f32_16x16x32_bf16(afr[ms][kf], bfr[kf], acc, 0, 0, 0);
#pragma unroll
            for (int r = 0; r < 4; ++r) {
                int btrow = bt0 + ms * 16 + quad * 4 + r;
                xg[dbase + (size_t)btrow * G4 + gate] = __float2bfloat16(acc[r] + bv);
            }
        }
    }
}

// ---------------------------------------------------------------------------
// Kernel 2: LSTM recurrence v11.
// v7 structure (proven stream-roofline scheduling) + two changes:
//  (1) AGPR weight residency: 8 kc (32 chunks = 128 words/thread) stashed in
//      AGPRs via explicit volatile v_accvgpr_write/read inline asm. Volatile
//      "a"-class defs cannot be rematerialized or hoisted -- this is the
//      residency tier rounds 1-6 could not get from the VGPR allocator.
//      Budget @2 waves/SIMD: 128 AGPR + ~110 arch VGPR < 256 unified cap.
//  (2) Early exit at L=seq_len[b]: outputs at t>=L are masked out of the
//      loss in both directions; k_fc/k_crf never read those rows.
// Residency: 8 kc AGPR + 4 kc LDS (131 KB) + 4 kc streamed (131 KB/step,
// down from v7's 393 KB -- the binding resource, ~112 B/cy/CU).
// ---------------------------------------------------------------------------
__global__ __launch_bounds__(512)
__attribute__((amdgpu_waves_per_eu(2, 2)))
void k_lstm(
    const __hip_bfloat16* __restrict__ xg,     // [2][B*T][1024] bf16
    const uint4* __restrict__ Wp,              // f16 packed [2][32][4][256]
    const int* __restrict__ seq_len,
    __hip_bfloat16* __restrict__ hcat)         // [B*T][512]
{
    int b = blockIdx.x & 63;
    int dir = blockIdx.x >> 6;
    int tid = threadIdx.x;      // 0..511
    int j   = tid & 255;
    int half = tid >> 8;        // K-half this thread reduces

    __shared__ __align__(16) uint4 wlds[16 * 512];        // 131072 B
    __shared__ __align__(16) _Float16 hbf[2][HH];         //   1024 B
    __shared__ float pbuf[4][HH];                         //   4096 B

    const uint4* Wd = Wp + (size_t)dir * (32 * 4 * 256);
    // chunk (kcl, g) of this thread lives at Ws[(kcl*4 + g)*256]
    const uint4* Ws = Wd + (size_t)(16 * half) * 4 * 256 + j;

    // ---- AGPR stash: kcl 0..7, 4 gates, 4 dwords each = 128 AGPRs
    unsigned ag[8][4][4];
#pragma unroll
    for (int kcl = 0; kcl < 8; ++kcl)
#pragma unroll
        for (int g = 0; g < 4; ++g) {
            uint4 w = Ws[(kcl * 4 + g) * 256];
            asm volatile("v_accvgpr_write_b32 %0, %1" : "=a"(ag[kcl][g][0]) : "v"(w.x));
            asm volatile("v_accvgpr_write_b32 %0, %1" : "=a"(ag[kcl][g][1]) : "v"(w.y));
            asm volatile("v_accvgpr_write_b32 %0, %1" : "=a"(ag[kcl][g][2]) : "v"(w.z));
            asm volatile("v_accvgpr_write_b32 %0, %1" : "=a"(ag[kcl][g][3]) : "v"(w.w));
        }

    // ---- LDS-resident: kcl 12..15
#pragma unroll
    for (int kcl = 12; kcl < 16; ++kcl)
#pragma unroll
        for (int g = 0; g < 4; ++g)
            wlds[((kcl - 12) * 4 + g) * 512 + tid] = Ws[(kcl * 4 + g) * 256];

    if (half == 0) hbf[0][j] = (_Float16)0.f;
    float c = 0.f;
    int L = seq_len[b];
    const __hip_bfloat16* xgb = xg + (size_t)dir * (size_t)(BB * TT * G4)
                                   + (size_t)b * TT * G4;

    int tc = dir ? (L - 1) : 0;
    float xv0 = 0.f, xv1 = 0.f, xv2 = 0.f, xv3 = 0.f;
    if (half == 0) {
        const __hip_bfloat16* xr = xgb + (size_t)tc * G4 + j;
        xv0 = __bfloat162float(xr[0]);   xv1 = __bfloat162float(xr[256]);
        xv2 = __bfloat162float(xr[512]); xv3 = __bfloat162float(xr[768]);
    }
    __syncthreads();

#pragma unroll 1
    for (int t = 0; t < L; ++t) {          // early exit: t>=L is masked out
        int cur = t & 1, nxt = cur ^ 1;
        int tn = t + 1;
        int tcn = dir ? ((tn < L) ? (L - 1 - tn) : tn) : tn;
        bool pf = (tn < L);
        __hip_bfloat16 p0, p1, p2, p3;
        if (half == 0 && pf) {
            const __hip_bfloat16* xr = xgb + (size_t)tcn * G4 + j;
            p0 = xr[0]; p1 = xr[256]; p2 = xr[512]; p3 = xr[768];
        }

        // launder offsets so stream/LDS weight reads stay inside the t-loop
        unsigned off = 0, soff = 0;
        asm volatile("" : "+v"(off), "+v"(soff));
        const uint4* Wst = (const uint4*)((const char*)Ws + soff);

        const _Float16* hrow = &hbf[cur][half * 128];
        float a0 = 0.f, a1 = 0.f, a2 = 0.f, a3 = 0.f;

        // --- AGPR-resident dots: kcl 0..7
#pragma unroll
        for (int kcl = 0; kcl < 8; ++kcl) {
            uint4 hv = *(const uint4*)(hrow + kcl * 8);   // wave-uniform bcast
            uint4 w0, w1, w2, w3;
            asm volatile(
                "v_accvgpr_read_b32 %0, %4\n\t"
                "v_accvgpr_read_b32 %1, %5\n\t"
                "v_accvgpr_read_b32 %2, %6\n\t"
                "v_accvgpr_read_b32 %3, %7"
                : "=v"(w0.x), "=v"(w0.y), "=v"(w0.z), "=v"(w0.w)
                : "a"(ag[kcl][0][0]), "a"(ag[kcl][0][1]),
                  "a"(ag[kcl][0][2]), "a"(ag[kcl][0][3]));
            asm volatile(
                "v_accvgpr_read_b32 %0, %4\n\t"
                "v_accvgpr_read_b32 %1, %5\n\t"
                "v_accvgpr_read_b32 %2, %6\n\t"
                "v_accvgpr_read_b32 %3, %7"
                : "=v"(w1.x), "=v"(w1.y), "=v"(w1.z), "=v"(w1.w)
                : "a"(ag[kcl][1][0]), "a"(ag[kcl][1][1]),
                  "a"(ag[kcl][1][2]), "a"(ag[kcl][1][3]));
            asm volatile(
                "v_accvgpr_read_b32 %0, %4\n\t"
                "v_accvgpr_read_b32 %1, %5\n\t"
                "v_accvgpr_read_b32 %2, %6\n\t"
                "v_accvgpr_read_b32 %3, %7"
                : "=v"(w2.x), "=v"(w2.y), "=v"(w2.z), "=v"(w2.w)
                : "a"(ag[kcl][2][0]), "a"(ag[kcl][2][1]),
                  "a"(ag[kcl][2][2]), "a"(ag[kcl][2][3]));
            asm volatile(
                "v_accvgpr_read_b32 %0, %4\n\t"
                "v_accvgpr_read_b32 %1, %5\n\t"
                "v_accvgpr_read_b32 %2, %6\n\t"
                "v_accvgpr_read_b32 %3, %7"
                : "=v"(w3.x), "=v"(w3.y), "=v"(w3.z), "=v"(w3.w)
                : "a"(ag[kcl][3][0]), "a"(ag[kcl][3][1]),
                  "a"(ag[kcl][3][2]), "a"(ag[kcl][3][3]));
            a0 = dot8(a0, w0, hv);
            a1 = dot8(a1, w1, hv);
            a2 = dot8(a2, w2, hv);
            a3 = dot8(a3, w3, hv);
        }

        // --- streamed dots: kcl 8..11 (131 KB/block/step from L2)
#pragma unroll
        for (int kcl = 8; kcl < 12; ++kcl) {
            uint4 hv = *(const uint4*)(hrow + kcl * 8);
            uint4 w0 = Wst[(kcl * 4 + 0) * 256];
            uint4 w1 = Wst[(kcl * 4 + 1) * 256];
            uint4 w2 = Wst[(kcl * 4 + 2) * 256];
            uint4 w3 = Wst[(kcl * 4 + 3) * 256];
            a0 = dot8(a0, w0, hv);
            a1 = dot8(a1, w1, hv);
            a2 = dot8(a2, w2, hv);
            a3 = dot8(a3, w3, hv);
        }

        // --- LDS-resident dots: kcl 12..15
#pragma unroll
        for (int kcl = 12; kcl < 16; ++kcl) {
            uint4 hv = *(const uint4*)(hrow + kcl * 8);
            int m0 = (kcl - 12) * 4;
            a0 = dot8(a0, wlds[(m0 + 0) * 512 + tid + off], hv);
            a1 = dot8(a1, wlds[(m0 + 1) * 512 + tid + off], hv);
            a2 = dot8(a2, wlds[(m0 + 2) * 512 + tid + off], hv);
            a3 = dot8(a3, wlds[(m0 + 3) * 512 + tid + off], hv);
        }

        if (half) {
            pbuf[0][j] = a0; pbuf[1][j] = a1;
            pbuf[2][j] = a2; pbuf[3][j] = a3;
        }
        __syncthreads();

        if (half == 0) {
            float gi = a0 + pbuf[0][j] + xv0;
            float gf = a1 + pbuf[1][j] + xv1;
            float gg = a2 + pbuf[2][j] + xv2;
            float go = a3 + pbuf[3][j] + xv3;
            float i_ = sigf(gi), f_ = sigf(gf), G = tanh_s(gg), o_ = sigf(go);
            c = f_ * c + i_ * G;
            float h = o_ * tanh_s(c);
            hbf[nxt][j] = (_Float16)h;
            hcat[((size_t)(b * TT + tc)) * (2 * HH) + dir * HH + j] = __float2bfloat16(h);
            if (pf) {
                xv0 = __bfloat162float(p0); xv1 = __bfloat162float(p1);
                xv2 = __bfloat162float(p2); xv3 = __bfloat162float(p3);
            }
        }
        tc = tcn;
        __syncthreads();
    }
}

// ---------------------------------------------------------------------------
// Kernel 3: feats = hcat @ fc_W^T + fc_b ; logits = log_softmax(feats)
// 4 rows per 256-thread block (one 64-lane wave-team per row).
// ---------------------------------------------------------------------------
__global__ __launch_bounds__(256) void k_fc(
    const __hip_bfloat16* __restrict__ hcat,
    const __hip_bfloat16* __restrict__ fcW,
    const float* __restrict__ fcb,
    float* __restrict__ logits)
{
    int team = threadIdx.x >> 6;   // 0..3
    int tid  = threadIdx.x & 63;
    int row  = blockIdx.x * 4 + team;
    __shared__ __align__(16) float hrow[4][2 * HH];
    __shared__ float fbuf[4][CC + 2];

    {
        uint4 v = *(const uint4*)(hcat + (size_t)row * (2 * HH) + tid * 8);
        float* d = &hrow[team][tid * 8];
        d[0] = bl16(v.x); d[1] = bh16(v.x);
        d[2] = bl16(v.y); d[3] = bh16(v.y);
        d[4] = bl16(v.z); d[5] = bh16(v.z);
        d[6] = bl16(v.w); d[7] = bh16(v.w);
    }
    __syncthreads();

    if (tid < CC) {
        float acc = fcb[tid];
        const uint4* wr = (const uint4*)(fcW + (size_t)tid * (2 * HH));
#pragma unroll 8
        for (int kc = 0; kc < 64; ++kc) {
            uint4 wv = wr[kc];
            float4 h0 = *(const float4*)&hrow[team][kc * 8];
            float4 h1 = *(const float4*)&hrow[team][kc * 8 + 4];
            acc = fmaf(bl16(wv.x), h0.x, acc); acc = fmaf(bh16(wv.x), h0.y, acc);
            acc = fmaf(bl16(wv.y), h0.z, acc); acc = fmaf(bh16(wv.y), h0.w, acc);
            acc = fmaf(bl16(wv.z), h1.x, acc); acc = fmaf(bh16(wv.z), h1.y, acc);
            acc = fmaf(bl16(wv.w), h1.z, acc); acc = fmaf(bh16(wv.w), h1.w, acc);
        }
        fbuf[team][tid] = acc;
    }
    __syncthreads();

    float m = -1e30f;
    for (int i = 0; i < CC; ++i) m = fmaxf(m, fbuf[team][i]);
    float s = 0.f;
    for (int i = 0; i < CC; ++i) s += __expf(fbuf[team][i] - m);
    float lns = __logf(s);
    if (tid < CC) logits[(size_t)row * CC + tid] = fbuf[team][tid] - m - lns;
}

// ---------------------------------------------------------------------------
// Kernel 4: CRF forward scan + gold score; per-batch loss -> loss_b[b]
// lg[t] row prefetched one iteration ahead (serial-scan critical path).
// ---------------------------------------------------------------------------
__global__ __launch_bounds__(256) void k_crf(
    const float* __restrict__ logits,
    const int* __restrict__ target,
    const int* __restrict__ seq_len,
    const float* __restrict__ trans,
    const float* __restrict__ start_s,
    const float* __restrict__ end_s,
    float* __restrict__ loss_b)
{
    const float L2E = 1.4426950408889634f;
    const float LN2 = 0.6931471805599453f;
    int b = blockIdx.x;
    int tid = threadIdx.x;
    int q = tid >> 6;
    int j = tid & 63;
    bool act = (j < CC);
    int L = seq_len[b];
    const float* lg = logits + (size_t)b * TT * CC;

    __shared__ float alpha2[64];
    __shared__ float mpart[4][64];
    __shared__ float spart[4][64];
    __shared__ float red[256];
    __shared__ float nbuf[CC + 2];

    int i0 = q * 13;
    int icnt = min(13, CC - i0);
    float treg[13];
    if (act) {
#pragma unroll
        for (int s = 0; s < 13; ++s)
            if (s < icnt) treg[s] = L2E * trans[(i0 + s) * CC + j];
    }
    if (q == 0 && act) alpha2[j] = L2E * (lg[j] + start_s[j]);
    __syncthreads();

    float v[13];
    float lgreg = 0.f;
    if (q == 0 && act) lgreg = lg[CC + j];          // row t=1
    for (int t = 1; t < L; ++t) {
        float lgnext = 0.f;
        if (q == 0 && act && (t + 1) < L)
            lgnext = lg[(size_t)(t + 1) * CC + j];  // prefetch next row

        float mq = -1e30f;
        if (act) {
#pragma unroll
            for (int s = 0; s < 13; ++s)
                if (s < icnt) { v[s] = alpha2[i0 + s] + treg[s]; mq = fmaxf(mq, v[s]); }
        }
        mpart[q][j] = mq;
        __syncthreads();
        float M = fmaxf(fmaxf(mpart[0][j], mpart[1][j]), fmaxf(mpart[2][j], mpart[3][j]));
        float sq = 0.f;
        if (act) {
#pragma unroll
            for (int s = 0; s < 13; ++s)
                if (s < icnt) sq += exp2f(v[s] - M);
        }
        spart[q][j] = sq;
        __syncthreads();
        if (q == 0 && act) {
            float S = spart[0][j] + spart[1][j] + spart[2][j] + spart[3][j];
            alpha2[j] = M + log2f(S) + L2E * lgreg;
        }
        lgreg = lgnext;
        __syncthreads();
    }

    if (q == 0 && act) nbuf[j] = alpha2[j] + L2E * end_s[j];

    float gp = 0.f;
    const int* tg = target + b * TT;
    for (int t = tid; t < TT; t += 256) {
        if (t < L) {
            int c = tg[t];
            gp += lg[(size_t)t * CC + c];
            if (t >= 1) gp += trans[tg[t - 1] * CC + c];
        }
    }
    red[tid] = gp;
    __syncthreads();

    if (tid == 0) {
        float m2 = -1e30f;
        for (int i = 0; i < CC; ++i) m2 = fmaxf(m2, nbuf[i]);
        float s2 = 0.f;
        for (int i = 0; i < CC; ++i) s2 += exp2f(nbuf[i] - m2);
        float norm_nat = (m2 + log2f(s2)) * LN2;
        float g = 0.f;
        for (int i = 0; i < 256; ++i) g += red[i];
        g += start_s[tg[0]] + end_s[tg[L - 1]];
        loss_b[b] = norm_nat - g;
    }
}

// Parallel final reduction (one wave)
__global__ void k_fin(const float* __restrict__ loss_b, float* __restrict__ out)
{
    int t = threadIdx.x;
    float v = loss_b[t];
#pragma unroll
    for (int o = 32; o > 0; o >>= 1) v += __shfl_down(v, o);
    if (t == 0) out[0] = v * (1.f / BB);
}

// ---------------------------------------------------------------------------
extern "C" void kernel_launch(void* const* d_in, const int* in_sizes, int n_in,
                              void* d_out, int out_size, void* d_ws, size_t ws_size,
                              hipStream_t stream)
{
    const int* words   = (const int*)d_in[0];
    const int* target  = (const int*)d_in[1];
    const int* seq_len = (const int*)d_in[2];
    const float* emb    = (const float*)d_in[3];
    const float* W_ih_f = (const float*)d_in[4];
    const float* W_hh_f = (const float*)d_in[5];
    const float* b_f    = (const float*)d_in[6];
    const float* W_ih_b = (const float*)d_in[7];
    const float* W_hh_b = (const float*)d_in[8];
    const float* b_b    = (const float*)d_in[9];
    const float* fc_W   = (const float*)d_in[10];
    const float* fc_b   = (const float*)d_in[11];
    const float* trans  = (const float*)d_in[12];
    const float* start_s= (const float*)d_in[13];
    const float* end_s  = (const float*)d_in[14];

    char* ws = (char*)d_ws;
    // workspace layout (bytes):
    //   xg     : 134217728                         @ 0
    //   hcat   :  33554432                         @ 134217728
    //   logits :   6553600                         @ 167772160
    //     (Wp f16 lstm pack, 1 MB, overlaps logits: consumed by k_lstm
    //      BEFORE k_fc writes logits)
    //   loss_b :       256                         @ 174325760
    //   wihall :    524288  (bf16 [2048][128])     @ 174326016
    //   fcw_bf :     51200                         @ 174850304
    __hip_bfloat16* xg     = (__hip_bfloat16*)ws;
    __hip_bfloat16* hcat   = (__hip_bfloat16*)(ws + 134217728);
    float*          logits = (float*)(ws + 167772160);
    uint4*          Wp     = (uint4*)(ws + 167772160);
    float*          loss_b = (float*)(ws + 174325760);
    __hip_bfloat16* wihall = (__hip_bfloat16*)(ws + 174326016);
    __hip_bfloat16* fcw_bf = (__hip_bfloat16*)(ws + 174850304);

    k_cvt<<<64,  256, 0, stream>>>(W_ih_f, wihall,          131072);
    k_cvt<<<64,  256, 0, stream>>>(W_ih_b, wihall + 131072, 131072);
    k_cvt<<<13,  256, 0, stream>>>(fc_W,   fcw_bf,          25600);
    k_pack<<<256, 256, 0, stream>>>(W_hh_f, W_hh_b, Wp);

    k_xg  <<<512, 256, 0, stream>>>(words, emb, wihall, b_f, b_b, xg);
    k_lstm<<<128, 512, 0, stream>>>(xg, Wp, seq_len, hcat);
    k_fc  <<<8192, 256, 0, stream>>>(hcat, fcw_bf, fc_b, logits);
    k_crf <<<64, 256, 0, stream>>>(logits, target, seq_len, trans, start_s, end_s, loss_b);
    k_fin <<<1, 64, 0, stream>>>(loss_b, (float*)d_out);
}